// Round 2
// baseline (900.338 us; speedup 1.0000x reference)
//
#include <hip/hip_runtime.h>
#include <hip/hip_bf16.h>

// B=8, C=512, G=32, HW=4096. All matrix dims are multiples of 128 -> no guards.
typedef __attribute__((ext_vector_type(8))) short short8;
typedef __attribute__((ext_vector_type(4))) float f32x4;

#define ALPHA 0.044194173824159216f

// global_load_lds helpers: LDS dest is wave-uniform base + lane*16 (linear).
#define GLO(p) (const __attribute__((address_space(1))) void*)(p)
#define LDSP(p) (__attribute__((address_space(3))) void*)(p)

__device__ __forceinline__ unsigned short f2bf(float f) {
    union { float f; unsigned int u; } c; c.f = f;
    unsigned int u = c.u;
    return (unsigned short)((u + 0x7FFFu + ((u >> 16) & 1u)) >> 16);
}

__device__ __forceinline__ float bf2f(unsigned short s) {
    union { unsigned int u; float f; } c; c.u = ((unsigned int)s) << 16;
    return c.f;
}

// ---------------- GroupNorm stats: one block per (b,g), 16ch x 4096 contiguous ----
__global__ __launch_bounds__(256) void gn_stats(const float* __restrict__ x,
                                                float* __restrict__ stats) {
    int blk = blockIdx.x;  // b*32 + g
    const float4* src = (const float4*)(x + (size_t)blk * 65536);
    float s = 0.f, sq = 0.f;
    for (int i = threadIdx.x; i < 16384; i += 256) {
        float4 v = src[i];
        s  += v.x + v.y + v.z + v.w;
        sq += v.x*v.x + v.y*v.y + v.z*v.z + v.w*v.w;
    }
    for (int off = 32; off; off >>= 1) {
        s  += __shfl_down(s, off);
        sq += __shfl_down(sq, off);
    }
    __shared__ float ss[4], ssq[4];
    int wid = threadIdx.x >> 6;
    if ((threadIdx.x & 63) == 0) { ss[wid] = s; ssq[wid] = sq; }
    __syncthreads();
    if (threadIdx.x == 0) {
        float S = ss[0]+ss[1]+ss[2]+ss[3], Q = ssq[0]+ssq[1]+ssq[2]+ssq[3];
        float mu = S * (1.f/65536.f);
        float var = Q * (1.f/65536.f) - mu*mu;
        stats[blk] = mu;
        stats[256 + blk] = rsqrtf(var + 1e-6f);
    }
}

// ---------------- weight fp32 -> bf16 ----------------
__global__ __launch_bounds__(256) void wcvt(const float* __restrict__ s,
                                            unsigned short* __restrict__ d) {
    int i = blockIdx.x * 1024 + threadIdx.x * 4;
    float4 v = *(const float4*)(s + i);
    ushort4 o = make_ushort4(f2bf(v.x), f2bf(v.y), f2bf(v.z), f2bf(v.w));
    *(ushort4*)(d + i) = o;
}

// ---------------- zero the softmax-denominator accumulator ----------------
__global__ __launch_bounds__(256) void zero_l(float* __restrict__ l) {
    ((float4*)l)[blockIdx.x * 256 + threadIdx.x] = make_float4(0.f, 0.f, 0.f, 0.f);
}

// ------- GN apply + transpose: x[b][c][hw] fp32 -> h[(b*4096+hw)][c] bf16 -------
__global__ __launch_bounds__(256) void gn_apply(const float* __restrict__ x,
                                                const float* __restrict__ stats,
                                                const float* __restrict__ gamma,
                                                const float* __restrict__ beta,
                                                unsigned short* __restrict__ h) {
    __shared__ unsigned short t[64][72];  // [hw_local][c_local], pad 72
    int b = blockIdx.z, c0 = blockIdx.y * 64, hw0 = blockIdx.x * 64;
    int tid = threadIdx.x;
#pragma unroll
    for (int rep = 0; rep < 4; ++rep) {
        int lin = rep * 256 + tid;         // 1024 = 64 c-rows x 16 float4
        int row = lin >> 4;                // c_local
        int c4  = lin & 15;                // float4 idx along hw
        int c   = c0 + row;
        const float4* src = (const float4*)(x + ((size_t)(b*512 + c) << 12) + hw0);
        float4 v = src[c4];
        int sidx = b*32 + (c >> 4);
        float mu = stats[sidx], rs = stats[256 + sidx];
        float ga = gamma[c] * rs, be = beta[c] - mu * ga;
        t[c4*4+0][row] = f2bf(v.x * ga + be);
        t[c4*4+1][row] = f2bf(v.y * ga + be);
        t[c4*4+2][row] = f2bf(v.z * ga + be);
        t[c4*4+3][row] = f2bf(v.w * ga + be);
    }
    __syncthreads();
#pragma unroll
    for (int rep = 0; rep < 2; ++rep) {
        int lin = rep * 256 + tid;         // 512 = 64 hw-rows x 8 groups
        int row = lin >> 3;                // hw_local
        int u8  = lin & 7;
        unsigned short* dst = h + (((size_t)(b*4096 + hw0 + row)) << 9) + c0 + u8*8;
        *(short8*)dst = *(const short8*)&t[row][u8*8];
    }
}

// ---------------- universal 128x128 bf16 MFMA GEMM, BK=64 ----------------
// Staging: global_load_lds width=16, linear LDS [128][64], both-sides XOR swizzle:
//   LDS slot s of row r holds logical col-group (s ^ (r&7)); global source column
//   is pre-permuted (((l&7) ^ (l>>3))*8) so the XOR'd ds_read returns correct data.
// C[m,n] = sum_k A[m,k] * B[n,k]
// mode 0: out bf16, out[m*ldo+n] = bf16((acc + bias[n]) * scale)          (q/k proj)
// mode 1: out bf16, out[m*ldo+n] = bf16(acc + bias[m])                    (vT proj)
// mode 2: out fp32 d_out[b][m][hw], n = b*4096+hw:
//           acc/lvec[n] + bias[m] + resid                                 (o-proj)
// mode 3: out bf16 P[m*ldo+n] = bf16(exp(acc)); atomicAdd row sums to lout (S pass)
__global__ __launch_bounds__(256, 2) void gemm_bt(const unsigned short* __restrict__ A,
                                                  int lda, long aZs,
                                                  const unsigned short* __restrict__ B,
                                                  int ldb, long bZs,
                                                  const float* __restrict__ bias,
                                                  const float* __restrict__ resid,
                                                  const float* __restrict__ lvec,
                                                  float* __restrict__ lout,
                                                  void* __restrict__ out,
                                                  long ldo, long oZs,
                                                  int K, int mode, float scale) {
    __shared__ unsigned short As[128][64], Bs[128][64];  // 32 KB linear
    int z = blockIdx.z;
    A += (size_t)z * aZs;
    B += (size_t)z * bZs;
    unsigned short* outu = (unsigned short*)out + (size_t)z * oZs;
    if (lout) lout += (size_t)z * 4096;
    int m0 = blockIdx.y * 128, n0 = blockIdx.x * 128;
    int tid = threadIdx.x, w = tid >> 6, l = tid & 63;
    int lr = l & 15, lq = l >> 4;
    int rsub = l >> 3, colp = ((l & 7) ^ rsub) << 3;   // pre-permuted source col
    int rbase = (w >> 1) * 64, cbase = (w & 1) * 64;
    int sw = (lr & 7) << 4;                             // read-side XOR
    f32x4 acc[4][4] = {};
    for (int k0 = 0; k0 < K; k0 += 64) {
        __syncthreads();
#pragma unroll
        for (int i = 0; i < 4; ++i) {
            int r = w * 32 + i * 8;                     // wave-uniform row base
            __builtin_amdgcn_global_load_lds(
                GLO(A + (size_t)(m0 + r + rsub) * lda + k0 + colp),
                LDSP(&As[r][0]), 16, 0, 0);
            __builtin_amdgcn_global_load_lds(
                GLO(B + (size_t)(n0 + r + rsub) * ldb + k0 + colp),
                LDSP(&Bs[r][0]), 16, 0, 0);
        }
        __syncthreads();
        const char* asb = (const char*)As;
        const char* bsb = (const char*)Bs;
        short8 af[4][2], bfv[4][2];
#pragma unroll
        for (int i = 0; i < 4; ++i)
#pragma unroll
            for (int ks = 0; ks < 2; ++ks) {
                int ra = rbase + i*16 + lr, rb = cbase + i*16 + lr;
                af[i][ks]  = *(const short8*)(asb + ((((ra << 7) + (ks << 6) + (lq << 4))) ^ sw));
                bfv[i][ks] = *(const short8*)(bsb + ((((rb << 7) + (ks << 6) + (lq << 4))) ^ sw));
            }
#pragma unroll
        for (int ks = 0; ks < 2; ++ks)
#pragma unroll
            for (int i = 0; i < 4; ++i)
#pragma unroll
                for (int j = 0; j < 4; ++j)
                    acc[i][j] = __builtin_amdgcn_mfma_f32_16x16x32_bf16(af[i][ks], bfv[j][ks], acc[i][j], 0, 0, 0);
    }
    // epilogue: C row = 4*lq + r (within 16-tile), col = lr
    int lq4 = lq * 4;
    if (mode == 3) {
#pragma unroll
        for (int i = 0; i < 4; ++i) {
            int rowl = rbase + i*16 + lq4;
#pragma unroll
            for (int r = 0; r < 4; ++r) {
                float s = 0.f;
#pragma unroll
                for (int j = 0; j < 4; ++j) {
                    float e = __expf(acc[i][j][r]);
                    s += e;
                    outu[(size_t)(m0 + rowl + r) * ldo + n0 + cbase + j*16 + lr] = f2bf(e);
                }
                s += __shfl_xor(s, 1); s += __shfl_xor(s, 2);
                s += __shfl_xor(s, 4); s += __shfl_xor(s, 8);
                if (lr == 0) atomicAdd(&lout[m0 + rowl + r], s);
            }
        }
        return;
    }
#pragma unroll
    for (int i = 0; i < 4; ++i) {
        int rowg = m0 + rbase + i*16 + lq4;
#pragma unroll
        for (int j = 0; j < 4; ++j) {
            int colg = n0 + cbase + j*16 + lr;
#pragma unroll
            for (int r = 0; r < 4; ++r) {
                float v = acc[i][j][r];
                int rr = rowg + r;
                if (mode == 0) {
                    outu[(size_t)rr * ldo + colg] = f2bf((v + bias[colg]) * scale);
                } else if (mode == 1) {
                    outu[(size_t)rr * ldo + colg] = f2bf(v + bias[rr]);
                } else {
                    size_t addr = ((size_t)(colg >> 12)) * 2097152 + (size_t)rr * 4096 + (colg & 4095);
                    ((float*)out)[addr] = v / lvec[colg] + bias[rr] + resid[addr];
                }
            }
        }
    }
}

// ---------------- P*V pass: 128x128 tiles, split-K=2, XCD-swizzled ----------------
// partial[s][z][m][n] = sum_{k in half s} P[z][m][k] * vt[n][(zofs+z)*4096 + k]
// P batches 0,1 at P0 (+z*16M), batches 2,3 at P1 (+(z-2)*16M).
// Grid nwg = nbatch*256 (split-K doubles block count -> 4 blocks/CU at nbatch=4).
// Bijective XCD swizzle: each XCD gets one contiguous (s,z) slab -> P panels L2-hit.
// Partials bf16 into dead qb/kb regions; addcvt combines them.
__global__ __launch_bounds__(256, 2) void gemm_pv(const unsigned short* __restrict__ P0,
                                                  const unsigned short* __restrict__ P1,
                                                  const unsigned short* __restrict__ vt,
                                                  unsigned short* __restrict__ part0,
                                                  unsigned short* __restrict__ part1,
                                                  int zofs, int nwg) {
    __shared__ unsigned short As[128][64], Bs[128][64];
    int wk = (int)(blockIdx.x & 7) * (nwg >> 3) + (int)(blockIdx.x >> 3);
    int half = nwg >> 1;
    int s = (wk >= half) ? 1 : 0;
    int rem = wk - s * half;
    int z = rem >> 7, t = rem & 127;
    int m0 = (t >> 2) << 7, n0 = (t & 3) << 7;
    int k0b = s << 11;                    // K-half start: 0 or 2048
    const unsigned short* A = (z < 2) ? P0 + (size_t)z * 16777216
                                      : P1 + (size_t)(z - 2) * 16777216;
    const unsigned short* vb = vt + (size_t)(zofs + z) * 4096;
    int tid = threadIdx.x, w = tid >> 6, l = tid & 63;
    int lr = l & 15, lq = l >> 4;
    int rsub = l >> 3, colp = ((l & 7) ^ rsub) << 3;
    int rbase = (w >> 1) * 64, cbase = (w & 1) * 64;
    int sw = (lr & 7) << 4;
    f32x4 acc[4][4] = {};
    for (int k0 = k0b; k0 < k0b + 2048; k0 += 64) {
        __syncthreads();
#pragma unroll
        for (int i = 0; i < 4; ++i) {
            int r = w * 32 + i * 8;
            __builtin_amdgcn_global_load_lds(
                GLO(A + (size_t)(m0 + r + rsub) * 4096 + k0 + colp),
                LDSP(&As[r][0]), 16, 0, 0);
            __builtin_amdgcn_global_load_lds(
                GLO(vb + (size_t)(n0 + r + rsub) * 32768 + k0 + colp),
                LDSP(&Bs[r][0]), 16, 0, 0);
        }
        __syncthreads();
        const char* asb = (const char*)As;
        const char* bsb = (const char*)Bs;
        short8 af[4][2], bfv[4][2];
#pragma unroll
        for (int i = 0; i < 4; ++i)
#pragma unroll
            for (int ks = 0; ks < 2; ++ks) {
                int ra = rbase + i*16 + lr, rb = cbase + i*16 + lr;
                af[i][ks]  = *(const short8*)(asb + ((((ra << 7) + (ks << 6) + (lq << 4))) ^ sw));
                bfv[i][ks] = *(const short8*)(bsb + ((((rb << 7) + (ks << 6) + (lq << 4))) ^ sw));
            }
#pragma unroll
        for (int ks = 0; ks < 2; ++ks)
#pragma unroll
            for (int i = 0; i < 4; ++i)
#pragma unroll
                for (int j = 0; j < 4; ++j)
                    acc[i][j] = __builtin_amdgcn_mfma_f32_16x16x32_bf16(af[i][ks], bfv[j][ks], acc[i][j], 0, 0, 0);
    }
    unsigned short* pp = (s ? part1 : part0) + ((size_t)z * 4096 + m0) * 512 + n0;
    int lq4 = lq * 4;
#pragma unroll
    for (int i = 0; i < 4; ++i)
#pragma unroll
        for (int j = 0; j < 4; ++j)
#pragma unroll
            for (int r = 0; r < 4; ++r)
                pp[(size_t)(rbase + i*16 + lq4 + r) * 512 + cbase + j*16 + lr] = f2bf(acc[i][j][r]);
}

// ---------------- combine split-K partials: o = bf16(p0 + p1) ----------------
__global__ __launch_bounds__(256) void addcvt(const unsigned short* __restrict__ p0,
                                              const unsigned short* __restrict__ p1,
                                              unsigned short* __restrict__ o) {
    size_t i = ((size_t)blockIdx.x * 256 + threadIdx.x) * 8;
    short8 a = *(const short8*)(p0 + i), b = *(const short8*)(p1 + i);
    short8 r;
#pragma unroll
    for (int j = 0; j < 8; ++j)
        r[j] = (short)f2bf(bf2f((unsigned short)a[j]) + bf2f((unsigned short)b[j]));
    *(short8*)(o + i) = r;
}

extern "C" void kernel_launch(void* const* d_in, const int* in_sizes, int n_in,
                              void* d_out, int out_size, void* d_ws, size_t ws_size,
                              hipStream_t stream) {
    const float* x     = (const float*)d_in[0];
    const float* gamma = (const float*)d_in[1];
    const float* beta  = (const float*)d_in[2];
    const float* wq = (const float*)d_in[3];  const float* bq = (const float*)d_in[4];
    const float* wk = (const float*)d_in[5];  const float* bk = (const float*)d_in[6];
    const float* wv = (const float*)d_in[7];  const float* bv = (const float*)d_in[8];
    const float* wo = (const float*)d_in[9];  const float* bo = (const float*)d_in[10];

    // ---- base workspace layout (proven, ends at 136,448,000 B) ----
    char* wsp = (char*)d_ws;
    float* stats        = (float*)wsp;                    //   2 KB
    unsigned short* wqb = (unsigned short*)(wsp + 2048);  // 512 KB each
    unsigned short* wkb = wqb + 262144;
    unsigned short* wvb = wkb + 262144;
    unsigned short* wob = wvb + 262144;
    unsigned short* h   = wob + 262144;                   // 32 MB [B*HW, C] bf16
    unsigned short* qb  = h  + 16777216;                  // 32 MB
    unsigned short* kb  = qb + 16777216;                  // 32 MB
    unsigned short* vtb = kb + 16777216;                  // 32 MB [C, B*HW] bf16
    float* lbuf         = (float*)(vtb + 16777216);       // 128 KB softmax denoms
    unsigned short* Pw  = (unsigned short*)(lbuf + 32768);// mid path: +64 MB, ends 203.6 MB
    unsigned short* Pd  = (unsigned short*)d_out;         // 64 MB: 2 batches of P
    unsigned short* ob  = h;                              // alias: h dead after vT GEMM

    // mid path needs 203,556,864 B total
    const bool mid = ws_size >= 204000000ull;

    gn_stats<<<256, 256, 0, stream>>>(x, stats);
    wcvt<<<256, 256, 0, stream>>>(wq, wqb);
    wcvt<<<256, 256, 0, stream>>>(wk, wkb);
    wcvt<<<256, 256, 0, stream>>>(wv, wvb);
    wcvt<<<256, 256, 0, stream>>>(wo, wob);
    gn_apply<<<dim3(64, 8, 8), 256, 0, stream>>>(x, stats, gamma, beta, h);
    zero_l<<<32, 256, 0, stream>>>(lbuf);

    // q = alpha*(h wq^T + bq), k = h wk^T + bk  : [32768 x 512]
    gemm_bt<<<dim3(4, 256), 256, 0, stream>>>(h, 512, 0, wqb, 512, 0, bq, nullptr, nullptr, nullptr,
                                              qb, 512, 0, 512, 0, ALPHA);
    gemm_bt<<<dim3(4, 256), 256, 0, stream>>>(h, 512, 0, wkb, 512, 0, bk, nullptr, nullptr, nullptr,
                                              kb, 512, 0, 512, 0, 1.0f);
    // vT[c, pos] = wv h^T + bv : [512 x 32768]
    gemm_bt<<<dim3(256, 4), 256, 0, stream>>>(wvb, 512, 0, h, 512, 0, bv, nullptr, nullptr, nullptr,
                                              vtb, 32768, 0, 512, 1, 1.0f);

    const long QS = (long)4096 * 512;   // per-batch q/k/o stride (elements)
    const long PS = (long)4096 * 4096;  // per-batch P stride
    if (mid) {
        // ---- 2 chunks x 4 batches: P in d_out (2) + ws tail (2) ----
        // After each chunk's S-passes, that chunk's qb/kb regions are dead ->
        // reuse as split-K partial buffers (16 MB each), then addcvt -> ob.
        for (int c = 0; c < 2; ++c) {
            size_t z0 = (size_t)c * 4;
            gemm_bt<<<dim3(32, 32, 2), 256, 0, stream>>>(
                qb + z0 * QS, 512, QS, kb + z0 * QS, 512, QS,
                nullptr, nullptr, nullptr, lbuf + z0 * 4096,
                Pd, 4096, PS, 512, 3, 1.0f);
            gemm_bt<<<dim3(32, 32, 2), 256, 0, stream>>>(
                qb + (z0 + 2) * QS, 512, QS, kb + (z0 + 2) * QS, 512, QS,
                nullptr, nullptr, nullptr, lbuf + (z0 + 2) * 4096,
                Pw, 4096, PS, 512, 3, 1.0f);
            gemm_pv<<<1024, 256, 0, stream>>>(Pd, Pw, vtb,
                                              qb + z0 * QS, kb + z0 * QS, (int)z0, 1024);
            addcvt<<<4096, 256, 0, stream>>>(qb + z0 * QS, kb + z0 * QS, ob + z0 * QS);
        }
    } else {
        // ---- 4 chunks x 2 batches: P in d_out only ----
        for (int c = 0; c < 4; ++c) {
            size_t z0 = (size_t)c * 2;
            gemm_bt<<<dim3(32, 32, 2), 256, 0, stream>>>(
                qb + z0 * QS, 512, QS, kb + z0 * QS, 512, QS,
                nullptr, nullptr, nullptr, lbuf + z0 * 4096,
                Pd, 4096, PS, 512, 3, 1.0f);
            gemm_pv<<<512, 256, 0, stream>>>(Pd, Pd, vtb,
                                             qb + z0 * QS, kb + z0 * QS, (int)z0, 512);
            addcvt<<<2048, 256, 0, stream>>>(qb + z0 * QS, kb + z0 * QS, ob + z0 * QS);
        }
    }
    // out[b,c,hw] = (wo o_unnorm^T)/l + bo + x   (overwrites all of d_out)
    gemm_bt<<<dim3(256, 4), 256, 0, stream>>>(wob, 512, 0, ob, 512, 0, bo, x, lbuf, nullptr,
                                              d_out, 0, 0, 512, 2, 1.0f);
}

// Round 3
// 820.921 us; speedup vs baseline: 1.0967x; 1.0967x over previous
//
#include <hip/hip_runtime.h>
#include <hip/hip_bf16.h>

// B=8, C=512, G=32, HW=4096. All matrix dims are multiples of 128 -> no guards.
typedef __attribute__((ext_vector_type(8))) short short8;
typedef __attribute__((ext_vector_type(4))) float f32x4;

#define ALPHA 0.044194173824159216f

// global_load_lds helpers: LDS dest is wave-uniform base + lane*16 (linear).
#define GLO(p) (const __attribute__((address_space(1))) void*)(p)
#define LDSP(p) (__attribute__((address_space(3))) void*)(p)

__device__ __forceinline__ unsigned short f2bf(float f) {
    union { float f; unsigned int u; } c; c.f = f;
    unsigned int u = c.u;
    return (unsigned short)((u + 0x7FFFu + ((u >> 16) & 1u)) >> 16);
}

// ---------------- GroupNorm stats: one block per (b,g), 16ch x 4096 contiguous ----
__global__ __launch_bounds__(256) void gn_stats(const float* __restrict__ x,
                                                float* __restrict__ stats) {
    int blk = blockIdx.x;  // b*32 + g
    const float4* src = (const float4*)(x + (size_t)blk * 65536);
    float s = 0.f, sq = 0.f;
    for (int i = threadIdx.x; i < 16384; i += 256) {
        float4 v = src[i];
        s  += v.x + v.y + v.z + v.w;
        sq += v.x*v.x + v.y*v.y + v.z*v.z + v.w*v.w;
    }
    for (int off = 32; off; off >>= 1) {
        s  += __shfl_down(s, off);
        sq += __shfl_down(sq, off);
    }
    __shared__ float ss[4], ssq[4];
    int wid = threadIdx.x >> 6;
    if ((threadIdx.x & 63) == 0) { ss[wid] = s; ssq[wid] = sq; }
    __syncthreads();
    if (threadIdx.x == 0) {
        float S = ss[0]+ss[1]+ss[2]+ss[3], Q = ssq[0]+ssq[1]+ssq[2]+ssq[3];
        float mu = S * (1.f/65536.f);
        float var = Q * (1.f/65536.f) - mu*mu;
        stats[blk] = mu;
        stats[256 + blk] = rsqrtf(var + 1e-6f);
    }
}

// ---------------- weight fp32 -> bf16 ----------------
__global__ __launch_bounds__(256) void wcvt(const float* __restrict__ s,
                                            unsigned short* __restrict__ d) {
    int i = blockIdx.x * 1024 + threadIdx.x * 4;
    float4 v = *(const float4*)(s + i);
    ushort4 o = make_ushort4(f2bf(v.x), f2bf(v.y), f2bf(v.z), f2bf(v.w));
    *(ushort4*)(d + i) = o;
}

// ---------------- zero the softmax-denominator accumulator ----------------
__global__ __launch_bounds__(256) void zero_l(float* __restrict__ l) {
    ((float4*)l)[blockIdx.x * 256 + threadIdx.x] = make_float4(0.f, 0.f, 0.f, 0.f);
}

// ------- GN apply + transpose: x[b][c][hw] fp32 -> h[(b*4096+hw)][c] bf16 -------
__global__ __launch_bounds__(256) void gn_apply(const float* __restrict__ x,
                                                const float* __restrict__ stats,
                                                const float* __restrict__ gamma,
                                                const float* __restrict__ beta,
                                                unsigned short* __restrict__ h) {
    __shared__ unsigned short t[64][72];  // [hw_local][c_local], pad 72
    int b = blockIdx.z, c0 = blockIdx.y * 64, hw0 = blockIdx.x * 64;
    int tid = threadIdx.x;
#pragma unroll
    for (int rep = 0; rep < 4; ++rep) {
        int lin = rep * 256 + tid;         // 1024 = 64 c-rows x 16 float4
        int row = lin >> 4;                // c_local
        int c4  = lin & 15;                // float4 idx along hw
        int c   = c0 + row;
        const float4* src = (const float4*)(x + ((size_t)(b*512 + c) << 12) + hw0);
        float4 v = src[c4];
        int sidx = b*32 + (c >> 4);
        float mu = stats[sidx], rs = stats[256 + sidx];
        float ga = gamma[c] * rs, be = beta[c] - mu * ga;
        t[c4*4+0][row] = f2bf(v.x * ga + be);
        t[c4*4+1][row] = f2bf(v.y * ga + be);
        t[c4*4+2][row] = f2bf(v.z * ga + be);
        t[c4*4+3][row] = f2bf(v.w * ga + be);
    }
    __syncthreads();
#pragma unroll
    for (int rep = 0; rep < 2; ++rep) {
        int lin = rep * 256 + tid;         // 512 = 64 hw-rows x 8 groups
        int row = lin >> 3;                // hw_local
        int u8  = lin & 7;
        unsigned short* dst = h + (((size_t)(b*4096 + hw0 + row)) << 9) + c0 + u8*8;
        *(short8*)dst = *(const short8*)&t[row][u8*8];
    }
}

// ---------------- universal 128x128 bf16 MFMA GEMM, BK=64 (reg-staged, proven) ----
// C[m,n] = sum_k A[m,k] * B[n,k]
// mode 0: out bf16, out[m*ldo+n] = bf16((acc + bias[n]) * scale)          (q/k proj)
// mode 1: out bf16, out[m*ldo+n] = bf16(acc + bias[m])                    (vT proj)
// mode 2: out fp32 d_out[b][m][hw], n = b*4096+hw:
//           acc/lvec[n] + bias[m] + resid                                 (o-proj)
// mode 3: out bf16 P[m*ldo+n] = bf16(exp(acc)); atomicAdd row sums to lout (S pass)
__global__ __launch_bounds__(256, 2) void gemm_bt(const unsigned short* __restrict__ A,
                                                  int lda, long aZs,
                                                  const unsigned short* __restrict__ B,
                                                  int ldb, long bZs,
                                                  const float* __restrict__ bias,
                                                  const float* __restrict__ resid,
                                                  const float* __restrict__ lvec,
                                                  float* __restrict__ lout,
                                                  void* __restrict__ out,
                                                  long ldo, long oZs,
                                                  int K, int mode, float scale) {
    __shared__ unsigned short As[128][72], Bs[128][72];  // 64-wide K-slab, pad 72
    int z = blockIdx.z;
    A += (size_t)z * aZs;
    B += (size_t)z * bZs;
    unsigned short* outu = (unsigned short*)out + (size_t)z * oZs;
    if (lout) lout += (size_t)z * 4096;
    int m0 = blockIdx.y * 128, n0 = blockIdx.x * 128;
    int tid = threadIdx.x, w = tid >> 6, l = tid & 63;
    int lr = l & 15, lq = l >> 4, lk = lq * 8;
    int rbase = (w >> 1) * 64, cbase = (w & 1) * 64;
    f32x4 acc[4][4] = {};
    for (int k0 = 0; k0 < K; k0 += 64) {
        __syncthreads();
#pragma unroll
        for (int p = 0; p < 4; ++p) {
            int lin = p * 256 + tid;           // 1024 = 128 rows x 8 short8
            int r = lin >> 3, qq = lin & 7;
            *(short8*)&As[r][qq*8] = *(const short8*)(A + (size_t)(m0 + r)*lda + k0 + qq*8);
            *(short8*)&Bs[r][qq*8] = *(const short8*)(B + (size_t)(n0 + r)*ldb + k0 + qq*8);
        }
        __syncthreads();
        short8 af[4][2], bfv[4][2];
#pragma unroll
        for (int i = 0; i < 4; ++i)
#pragma unroll
            for (int ks = 0; ks < 2; ++ks) {
                af[i][ks]  = *(const short8*)&As[rbase + i*16 + lr][ks*32 + lk];
                bfv[i][ks] = *(const short8*)&Bs[cbase + i*16 + lr][ks*32 + lk];
            }
#pragma unroll
        for (int ks = 0; ks < 2; ++ks)
#pragma unroll
            for (int i = 0; i < 4; ++i)
#pragma unroll
                for (int j = 0; j < 4; ++j)
                    acc[i][j] = __builtin_amdgcn_mfma_f32_16x16x32_bf16(af[i][ks], bfv[j][ks], acc[i][j], 0, 0, 0);
    }
    // epilogue: C row = 4*lq + r (within 16-tile), col = lr
    int lq4 = lq * 4;
    if (mode == 3) {
#pragma unroll
        for (int i = 0; i < 4; ++i) {
            int rowl = rbase + i*16 + lq4;
#pragma unroll
            for (int r = 0; r < 4; ++r) {
                float s = 0.f;
#pragma unroll
                for (int j = 0; j < 4; ++j) {
                    float e = __expf(acc[i][j][r]);
                    s += e;
                    outu[(size_t)(m0 + rowl + r) * ldo + n0 + cbase + j*16 + lr] = f2bf(e);
                }
                s += __shfl_xor(s, 1); s += __shfl_xor(s, 2);
                s += __shfl_xor(s, 4); s += __shfl_xor(s, 8);
                if (lr == 0) atomicAdd(&lout[m0 + rowl + r], s);
            }
        }
        return;
    }
#pragma unroll
    for (int i = 0; i < 4; ++i) {
        int rowg = m0 + rbase + i*16 + lq4;
#pragma unroll
        for (int j = 0; j < 4; ++j) {
            int colg = n0 + cbase + j*16 + lr;
#pragma unroll
            for (int r = 0; r < 4; ++r) {
                float v = acc[i][j][r];
                int rr = rowg + r;
                if (mode == 0) {
                    outu[(size_t)rr * ldo + colg] = f2bf((v + bias[colg]) * scale);
                } else if (mode == 1) {
                    outu[(size_t)rr * ldo + colg] = f2bf(v + bias[rr]);
                } else {
                    size_t addr = ((size_t)(colg >> 12)) * 2097152 + (size_t)rr * 4096 + (colg & 4095);
                    ((float*)out)[addr] = v / lvec[colg] + bias[rr] + resid[addr];
                }
            }
        }
    }
}

// ---------------- P*V pass: 128x128 tiles, double-buffered gload_lds ----------------
// o[(zofs+z)*4096 + m][n] = sum_k P[z][m][k] * vt[n][(zofs+z)*4096 + k]
// P batches 0,1 at P0 (+z*16M), batches 2,3 at P1 (+(z-2)*16M).
// Staging: global_load_lds w=16, linear LDS, both-sides XOR swizzle (verified R2):
//   source col pre-permuted ((l&7)^(l>>3))*8, read addr ^ (lr&7)<<4 -> 0 conflicts.
// Pipeline: stage(t+1) issued BEFORE compute(t); single __syncthreads per K-step
//   drains the overlapped loads. 64 KB LDS -> 2 blocks/CU; grid = one resident round.
// Bijective XCD swizzle: 4 consecutive n-blocks share a P m-panel on one XCD's L2.
__global__ __launch_bounds__(256, 2) void gemm_pv(const unsigned short* __restrict__ P0,
                                                  const unsigned short* __restrict__ P1,
                                                  const unsigned short* __restrict__ vt,
                                                  unsigned short* __restrict__ o,
                                                  int zofs, int nwg) {
    __shared__ unsigned short As[2][128][64], Bs[2][128][64];  // 64 KB
    int wk = (int)(blockIdx.x & 7) * (nwg >> 3) + (int)(blockIdx.x >> 3);
    int z = wk >> 7, t = wk & 127;
    int m0 = (t >> 2) << 7, n0 = (t & 3) << 7;
    const unsigned short* A = (z < 2) ? P0 + (size_t)z * 16777216
                                      : P1 + (size_t)(z - 2) * 16777216;
    int zb = zofs + z;
    const unsigned short* vb = vt + (size_t)zb * 4096;
    int tid = threadIdx.x, w = tid >> 6, l = tid & 63;
    int lr = l & 15, lq = l >> 4;
    int rsub = l >> 3, colp = ((l & 7) ^ rsub) << 3;   // pre-permuted source col
    int rbase = (w >> 1) * 64, cbase = (w & 1) * 64;
    int sw = (lr & 7) << 4;                             // read-side XOR
    int rw = w * 32;                                    // wave's staging row base
    f32x4 acc[4][4] = {};
    // prologue: stage tile 0 into buffer 0
#pragma unroll
    for (int i = 0; i < 4; ++i) {
        int r = rw + i * 8;
        __builtin_amdgcn_global_load_lds(
            GLO(A + (size_t)(m0 + r + rsub) * 4096 + colp),
            LDSP(&As[0][r][0]), 16, 0, 0);
        __builtin_amdgcn_global_load_lds(
            GLO(vb + (size_t)(n0 + r + rsub) * 32768 + colp),
            LDSP(&Bs[0][r][0]), 16, 0, 0);
    }
    __syncthreads();
    for (int ti = 0; ti < 64; ++ti) {
        int cur = ti & 1;
        if (ti < 63) {
            int k1 = (ti + 1) << 6;
#pragma unroll
            for (int i = 0; i < 4; ++i) {
                int r = rw + i * 8;
                __builtin_amdgcn_global_load_lds(
                    GLO(A + (size_t)(m0 + r + rsub) * 4096 + k1 + colp),
                    LDSP(&As[cur ^ 1][r][0]), 16, 0, 0);
                __builtin_amdgcn_global_load_lds(
                    GLO(vb + (size_t)(n0 + r + rsub) * 32768 + k1 + colp),
                    LDSP(&Bs[cur ^ 1][r][0]), 16, 0, 0);
            }
        }
        const char* asb = (const char*)As + cur * 16384;
        const char* bsb = (const char*)Bs + cur * 16384;
        short8 af[4][2], bfv[4][2];
#pragma unroll
        for (int i = 0; i < 4; ++i)
#pragma unroll
            for (int ks = 0; ks < 2; ++ks) {
                int ra = rbase + i*16 + lr, rb = cbase + i*16 + lr;
                af[i][ks]  = *(const short8*)(asb + ((((ra << 7) + (ks << 6) + (lq << 4))) ^ sw));
                bfv[i][ks] = *(const short8*)(bsb + ((((rb << 7) + (ks << 6) + (lq << 4))) ^ sw));
            }
#pragma unroll
        for (int ks = 0; ks < 2; ++ks)
#pragma unroll
            for (int i = 0; i < 4; ++i)
#pragma unroll
                for (int j = 0; j < 4; ++j)
                    acc[i][j] = __builtin_amdgcn_mfma_f32_16x16x32_bf16(af[i][ks], bfv[j][ks], acc[i][j], 0, 0, 0);
        __syncthreads();
    }
    unsigned short* ob = o + ((size_t)zb * 4096 + m0) * 512 + n0;
    int lq4 = lq * 4;
#pragma unroll
    for (int i = 0; i < 4; ++i)
#pragma unroll
        for (int j = 0; j < 4; ++j)
#pragma unroll
            for (int r = 0; r < 4; ++r)
                ob[(size_t)(rbase + i*16 + lq4 + r) * 512 + cbase + j*16 + lr] = f2bf(acc[i][j][r]);
}

extern "C" void kernel_launch(void* const* d_in, const int* in_sizes, int n_in,
                              void* d_out, int out_size, void* d_ws, size_t ws_size,
                              hipStream_t stream) {
    const float* x     = (const float*)d_in[0];
    const float* gamma = (const float*)d_in[1];
    const float* beta  = (const float*)d_in[2];
    const float* wq = (const float*)d_in[3];  const float* bq = (const float*)d_in[4];
    const float* wk = (const float*)d_in[5];  const float* bk = (const float*)d_in[6];
    const float* wv = (const float*)d_in[7];  const float* bv = (const float*)d_in[8];
    const float* wo = (const float*)d_in[9];  const float* bo = (const float*)d_in[10];

    // ---- base workspace layout (proven, ends at 136,448,000 B) ----
    char* wsp = (char*)d_ws;
    float* stats        = (float*)wsp;                    //   2 KB
    unsigned short* wqb = (unsigned short*)(wsp + 2048);  // 512 KB each
    unsigned short* wkb = wqb + 262144;
    unsigned short* wvb = wkb + 262144;
    unsigned short* wob = wvb + 262144;
    unsigned short* h   = wob + 262144;                   // 32 MB [B*HW, C] bf16
    unsigned short* qb  = h  + 16777216;                  // 32 MB
    unsigned short* kb  = qb + 16777216;                  // 32 MB
    unsigned short* vtb = kb + 16777216;                  // 32 MB [C, B*HW] bf16
    float* lbuf         = (float*)(vtb + 16777216);       // 128 KB softmax denoms
    unsigned short* Pw  = (unsigned short*)(lbuf + 32768);// mid path: +64 MB, ends 203.6 MB
    unsigned short* Pd  = (unsigned short*)d_out;         // 64 MB: 2 batches of P
    unsigned short* ob  = h;                              // alias: h dead after vT GEMM

    // mid path needs 203,556,864 B total
    const bool mid = ws_size >= 204000000ull;

    gn_stats<<<256, 256, 0, stream>>>(x, stats);
    wcvt<<<256, 256, 0, stream>>>(wq, wqb);
    wcvt<<<256, 256, 0, stream>>>(wk, wkb);
    wcvt<<<256, 256, 0, stream>>>(wv, wvb);
    wcvt<<<256, 256, 0, stream>>>(wo, wob);
    gn_apply<<<dim3(64, 8, 8), 256, 0, stream>>>(x, stats, gamma, beta, h);
    zero_l<<<32, 256, 0, stream>>>(lbuf);

    // q = alpha*(h wq^T + bq), k = h wk^T + bk  : [32768 x 512]
    gemm_bt<<<dim3(4, 256), 256, 0, stream>>>(h, 512, 0, wqb, 512, 0, bq, nullptr, nullptr, nullptr,
                                              qb, 512, 0, 512, 0, ALPHA);
    gemm_bt<<<dim3(4, 256), 256, 0, stream>>>(h, 512, 0, wkb, 512, 0, bk, nullptr, nullptr, nullptr,
                                              kb, 512, 0, 512, 0, 1.0f);
    // vT[c, pos] = wv h^T + bv : [512 x 32768]
    gemm_bt<<<dim3(256, 4), 256, 0, stream>>>(wvb, 512, 0, h, 512, 0, bv, nullptr, nullptr, nullptr,
                                              vtb, 32768, 0, 512, 1, 1.0f);

    const long QS = (long)4096 * 512;   // per-batch q/k/o stride
    const long PS = (long)4096 * 4096;  // per-batch P stride
    if (mid) {
        // ---- 2 chunks x 4 batches: P in d_out (2) + ws tail (2); PV at 512 blocks ----
        for (int c = 0; c < 2; ++c) {
            size_t z0 = (size_t)c * 4;
            gemm_bt<<<dim3(32, 32, 2), 256, 0, stream>>>(
                qb + z0 * QS, 512, QS, kb + z0 * QS, 512, QS,
                nullptr, nullptr, nullptr, lbuf + z0 * 4096,
                Pd, 4096, PS, 512, 3, 1.0f);
            gemm_bt<<<dim3(32, 32, 2), 256, 0, stream>>>(
                qb + (z0 + 2) * QS, 512, QS, kb + (z0 + 2) * QS, 512, QS,
                nullptr, nullptr, nullptr, lbuf + (z0 + 2) * 4096,
                Pw, 4096, PS, 512, 3, 1.0f);
            gemm_pv<<<512, 256, 0, stream>>>(Pd, Pw, vtb, ob, (int)z0, 512);
        }
    } else {
        // ---- 4 chunks x 2 batches: P in d_out only; PV at 256 blocks ----
        for (int c = 0; c < 4; ++c) {
            size_t z0 = (size_t)c * 2;
            gemm_bt<<<dim3(32, 32, 2), 256, 0, stream>>>(
                qb + z0 * QS, 512, QS, kb + z0 * QS, 512, QS,
                nullptr, nullptr, nullptr, lbuf + z0 * 4096,
                Pd, 4096, PS, 512, 3, 1.0f);
            gemm_pv<<<256, 256, 0, stream>>>(Pd, Pd, vtb, ob, (int)z0, 256);
        }
    }
    // out[b,c,hw] = (wo o_unnorm^T)/l + bo + x   (overwrites all of d_out)
    gemm_bt<<<dim3(256, 4), 256, 0, stream>>>(wob, 512, 0, ob, 512, 0, bo, x, lbuf, nullptr,
                                              d_out, 0, 0, 512, 2, 1.0f);
}

// Round 5
// 802.803 us; speedup vs baseline: 1.1215x; 1.0226x over previous
//
#include <hip/hip_runtime.h>
#include <hip/hip_bf16.h>

// B=8, C=512, G=32, HW=4096. All matrix dims are multiples of 128 -> no guards.
typedef __attribute__((ext_vector_type(8))) short short8;
typedef __attribute__((ext_vector_type(4))) float f32x4;

#define ALPHA 0.044194173824159216f

// global_load_lds helpers: LDS dest is wave-uniform base + lane*16 (linear).
#define GLO(p) (const __attribute__((address_space(1))) void*)(p)
#define LDSP(p) (__attribute__((address_space(3))) void*)(p)

__device__ __forceinline__ unsigned short f2bf(float f) {
    union { float f; unsigned int u; } c; c.f = f;
    unsigned int u = c.u;
    return (unsigned short)((u + 0x7FFFu + ((u >> 16) & 1u)) >> 16);
}

__device__ __forceinline__ float bf2f(unsigned short s) {
    union { unsigned int u; float f; } c; c.u = ((unsigned int)s) << 16;
    return c.f;
}

// ---------------- GroupNorm stats: one block per (b,g), 16ch x 4096 contiguous ----
__global__ __launch_bounds__(256) void gn_stats(const float* __restrict__ x,
                                                float* __restrict__ stats) {
    int blk = blockIdx.x;  // b*32 + g
    const float4* src = (const float4*)(x + (size_t)blk * 65536);
    float s = 0.f, sq = 0.f;
    for (int i = threadIdx.x; i < 16384; i += 256) {
        float4 v = src[i];
        s  += v.x + v.y + v.z + v.w;
        sq += v.x*v.x + v.y*v.y + v.z*v.z + v.w*v.w;
    }
    for (int off = 32; off; off >>= 1) {
        s  += __shfl_down(s, off);
        sq += __shfl_down(sq, off);
    }
    __shared__ float ss[4], ssq[4];
    int wid = threadIdx.x >> 6;
    if ((threadIdx.x & 63) == 0) { ss[wid] = s; ssq[wid] = sq; }
    __syncthreads();
    if (threadIdx.x == 0) {
        float S = ss[0]+ss[1]+ss[2]+ss[3], Q = ssq[0]+ssq[1]+ssq[2]+ssq[3];
        float mu = S * (1.f/65536.f);
        float var = Q * (1.f/65536.f) - mu*mu;
        stats[blk] = mu;
        stats[256 + blk] = rsqrtf(var + 1e-6f);
    }
}

// ---------------- weight fp32 -> bf16 ----------------
__global__ __launch_bounds__(256) void wcvt(const float* __restrict__ s,
                                            unsigned short* __restrict__ d) {
    int i = blockIdx.x * 1024 + threadIdx.x * 4;
    float4 v = *(const float4*)(s + i);
    ushort4 o = make_ushort4(f2bf(v.x), f2bf(v.y), f2bf(v.z), f2bf(v.w));
    *(ushort4*)(d + i) = o;
}

// ---------------- zero the softmax-denominator accumulator ----------------
__global__ __launch_bounds__(256) void zero_l(float* __restrict__ l) {
    ((float4*)l)[blockIdx.x * 256 + threadIdx.x] = make_float4(0.f, 0.f, 0.f, 0.f);
}

// ------- GN apply + transpose: x[b][c][hw] fp32 -> h[(b*4096+hw)][c] bf16 -------
__global__ __launch_bounds__(256) void gn_apply(const float* __restrict__ x,
                                                const float* __restrict__ stats,
                                                const float* __restrict__ gamma,
                                                const float* __restrict__ beta,
                                                unsigned short* __restrict__ h) {
    __shared__ unsigned short t[64][72];  // [hw_local][c_local], pad 72
    int b = blockIdx.z, c0 = blockIdx.y * 64, hw0 = blockIdx.x * 64;
    int tid = threadIdx.x;
#pragma unroll
    for (int rep = 0; rep < 4; ++rep) {
        int lin = rep * 256 + tid;         // 1024 = 64 c-rows x 16 float4
        int row = lin >> 4;                // c_local
        int c4  = lin & 15;                // float4 idx along hw
        int c   = c0 + row;
        const float4* src = (const float4*)(x + ((size_t)(b*512 + c) << 12) + hw0);
        float4 v = src[c4];
        int sidx = b*32 + (c >> 4);
        float mu = stats[sidx], rs = stats[256 + sidx];
        float ga = gamma[c] * rs, be = beta[c] - mu * ga;
        t[c4*4+0][row] = f2bf(v.x * ga + be);
        t[c4*4+1][row] = f2bf(v.y * ga + be);
        t[c4*4+2][row] = f2bf(v.z * ga + be);
        t[c4*4+3][row] = f2bf(v.w * ga + be);
    }
    __syncthreads();
#pragma unroll
    for (int rep = 0; rep < 2; ++rep) {
        int lin = rep * 256 + tid;         // 512 = 64 hw-rows x 8 groups
        int row = lin >> 3;                // hw_local
        int u8  = lin & 7;
        unsigned short* dst = h + (((size_t)(b*4096 + hw0 + row)) << 9) + c0 + u8*8;
        *(short8*)dst = *(const short8*)&t[row][u8*8];
    }
}

// ---------------- universal 128x128 bf16 MFMA GEMM, BK=64 (reg-staged, proven) ----
// C[m,n] = sum_k A[m,k] * B[n,k]
// mode 0: out bf16, out[m*ldo+n] = bf16((acc + bias[n]) * scale)          (q/k proj)
// mode 1: out bf16, out[m*ldo+n] = bf16(acc + bias[m])                    (vT proj)
// mode 2: out fp32 d_out[b][m][hw], n = b*4096+hw:
//           acc/lvec[n] + bias[m] + resid                                 (o-proj)
__global__ __launch_bounds__(256, 2) void gemm_bt(const unsigned short* __restrict__ A,
                                                  int lda, long aZs,
                                                  const unsigned short* __restrict__ B,
                                                  int ldb, long bZs,
                                                  const float* __restrict__ bias,
                                                  const float* __restrict__ resid,
                                                  const float* __restrict__ lvec,
                                                  void* __restrict__ out,
                                                  long ldo, long oZs,
                                                  int K, int mode, float scale) {
    __shared__ unsigned short As[128][72], Bs[128][72];  // 64-wide K-slab, pad 72
    int z = blockIdx.z;
    A += (size_t)z * aZs;
    B += (size_t)z * bZs;
    unsigned short* outu = (unsigned short*)out + (size_t)z * oZs;
    int m0 = blockIdx.y * 128, n0 = blockIdx.x * 128;
    int tid = threadIdx.x, w = tid >> 6, l = tid & 63;
    int lr = l & 15, lq = l >> 4, lk = lq * 8;
    int rbase = (w >> 1) * 64, cbase = (w & 1) * 64;
    f32x4 acc[4][4] = {};
    for (int k0 = 0; k0 < K; k0 += 64) {
        __syncthreads();
#pragma unroll
        for (int p = 0; p < 4; ++p) {
            int lin = p * 256 + tid;           // 1024 = 128 rows x 8 short8
            int r = lin >> 3, qq = lin & 7;
            *(short8*)&As[r][qq*8] = *(const short8*)(A + (size_t)(m0 + r)*lda + k0 + qq*8);
            *(short8*)&Bs[r][qq*8] = *(const short8*)(B + (size_t)(n0 + r)*ldb + k0 + qq*8);
        }
        __syncthreads();
        short8 af[4][2], bfv[4][2];
#pragma unroll
        for (int i = 0; i < 4; ++i)
#pragma unroll
            for (int ks = 0; ks < 2; ++ks) {
                af[i][ks]  = *(const short8*)&As[rbase + i*16 + lr][ks*32 + lk];
                bfv[i][ks] = *(const short8*)&Bs[cbase + i*16 + lr][ks*32 + lk];
            }
#pragma unroll
        for (int ks = 0; ks < 2; ++ks)
#pragma unroll
            for (int i = 0; i < 4; ++i)
#pragma unroll
                for (int j = 0; j < 4; ++j)
                    acc[i][j] = __builtin_amdgcn_mfma_f32_16x16x32_bf16(af[i][ks], bfv[j][ks], acc[i][j], 0, 0, 0);
    }
    int lq4 = lq * 4;
#pragma unroll
    for (int i = 0; i < 4; ++i) {
        int rowg = m0 + rbase + i*16 + lq4;
#pragma unroll
        for (int j = 0; j < 4; ++j) {
            int colg = n0 + cbase + j*16 + lr;
#pragma unroll
            for (int r = 0; r < 4; ++r) {
                float v = acc[i][j][r];
                int rr = rowg + r;
                if (mode == 0) {
                    outu[(size_t)rr * ldo + colg] = f2bf((v + bias[colg]) * scale);
                } else if (mode == 1) {
                    outu[(size_t)rr * ldo + colg] = f2bf(v + bias[rr]);
                } else {
                    size_t addr = ((size_t)(colg >> 12)) * 2097152 + (size_t)rr * 4096 + (colg & 4095);
                    ((float*)out)[addr] = v / lvec[colg] + bias[rr] + resid[addr];
                }
            }
        }
    }
}

// =====================================================================
// 8-phase-style 256x256 MFMA core (T1+T2+T3+T4+T5), BK=64, 512 thr, 8 waves (2Mx4N)
// LDS 128 KiB: As/Bs [2][256][64] linear, both-sides XOR swizzle (verified 0-conflict
// in R2/R3 PV): source col pre-permuted ((l&7)^(l>>3))*8; read addr ^ (lr&7)<<4.
// Staging ledger (2 buffers, hazard-audited):
//   phase 1 of tile t: read all B-frags + A m-pair0; issue A(t+1) -> buf^1.  [4 loads]
//   phase 2: read A m-pair1; issue B-half0(t+2) -> buf cur (B read in ph1).  [2 loads]
//   phase 3: read A m-pair2; issue B-half1(t+2).                             [2 loads]
//   phase 4: read A m-pair3; vmcnt(4): drains B(t+1)+A(t+1), leaves B(t+2)
//     in flight. NEVER vmcnt(0) in steady state (T4).
// Each phase: lgkmcnt(0)+sched_barrier (rule #18), s_barrier, setprio(1),
// 16 MFMA, setprio(0), s_barrier.
// =====================================================================
__device__ __forceinline__ void mm8_core(const unsigned short* __restrict__ A, int lda,
                                         const unsigned short* __restrict__ B, int ldb,
                                         int T,
                                         unsigned short (*As)[256][64],
                                         unsigned short (*Bs)[256][64],
                                         f32x4 acc[8][4]) {
    int tid = threadIdx.x, w = tid >> 6, l = tid & 63;
    int wr = w >> 2, wc = w & 3;
    int lr = l & 15, lq = l >> 4;
    int rsub = l >> 3, colp = ((l & 7) ^ rsub) << 3;   // pre-permuted source col
    int sw = (lr & 7) << 4;                             // read-side XOR
    int aw = w * 8;                                     // wave row offset in 64-row span

#define SG_A(buf, t_) { \
    const unsigned short* ap = A + (size_t)(t_) * 64; \
    __builtin_amdgcn_global_load_lds(GLO(ap + (size_t)(aw + rsub) * lda + colp),        LDSP(&As[buf][aw][0]), 16, 0, 0); \
    __builtin_amdgcn_global_load_lds(GLO(ap + (size_t)(64 + aw + rsub) * lda + colp),   LDSP(&As[buf][64 + aw][0]), 16, 0, 0); \
    __builtin_amdgcn_global_load_lds(GLO(ap + (size_t)(128 + aw + rsub) * lda + colp),  LDSP(&As[buf][128 + aw][0]), 16, 0, 0); \
    __builtin_amdgcn_global_load_lds(GLO(ap + (size_t)(192 + aw + rsub) * lda + colp),  LDSP(&As[buf][192 + aw][0]), 16, 0, 0); }
#define SG_B(buf, t_, h_) { \
    const unsigned short* bp = B + (size_t)(t_) * 64; int rb = (h_) * 128 + aw; \
    __builtin_amdgcn_global_load_lds(GLO(bp + (size_t)(rb + rsub) * ldb + colp),       LDSP(&Bs[buf][rb][0]), 16, 0, 0); \
    __builtin_amdgcn_global_load_lds(GLO(bp + (size_t)(rb + 64 + rsub) * ldb + colp),  LDSP(&Bs[buf][rb + 64][0]), 16, 0, 0); }
#define RD_B() { \
    const char* bsb = (const char*)Bs[cur]; \
    _Pragma("unroll") for (int nj = 0; nj < 4; ++nj) \
    _Pragma("unroll") for (int ks = 0; ks < 2; ++ks) { \
        int row = wc * 64 + nj * 16 + lr; \
        bf[nj][ks] = *(const short8*)(bsb + (((row << 7) + (ks << 6) + (lq << 4)) ^ sw)); } }
#define RD_A(p_) { \
    const char* asb = (const char*)As[cur]; \
    _Pragma("unroll") for (int i = 0; i < 2; ++i) \
    _Pragma("unroll") for (int ks = 0; ks < 2; ++ks) { \
        int row = wr * 128 + ((p_) * 2 + i) * 16 + lr; \
        af[i][ks] = *(const short8*)(asb + (((row << 7) + (ks << 6) + (lq << 4)) ^ sw)); } }
#define MM(p_) { \
    _Pragma("unroll") for (int ks = 0; ks < 2; ++ks) \
    _Pragma("unroll") for (int i = 0; i < 2; ++i) \
    _Pragma("unroll") for (int nj = 0; nj < 4; ++nj) \
        acc[(p_) * 2 + i][nj] = __builtin_amdgcn_mfma_f32_16x16x32_bf16(af[i][ks], bf[nj][ks], acc[(p_) * 2 + i][nj], 0, 0, 0); }
#define LGKM0 { asm volatile("s_waitcnt lgkmcnt(0)" ::: "memory"); __builtin_amdgcn_sched_barrier(0); }
#define VMC4 { asm volatile("s_waitcnt vmcnt(4)" ::: "memory"); __builtin_amdgcn_sched_barrier(0); }
#define VMC0 { asm volatile("s_waitcnt vmcnt(0)" ::: "memory"); __builtin_amdgcn_sched_barrier(0); }
#define BAR __builtin_amdgcn_s_barrier()

    // prologue: tile 0 (A+B) -> buf0; B(1) -> buf1; drain tile 0, keep B(1) in flight
    SG_A(0, 0); SG_B(0, 0, 0); SG_B(0, 0, 1);
    if (T > 1) { SG_B(1, 1, 0); SG_B(1, 1, 1); VMC4; } else { VMC0; }
    BAR;
    for (int t = 0; t < T; ++t) {
        int cur = t & 1, nxt = cur ^ 1;
        short8 bf[4][2], af[2][2];
        // phase 1
        RD_B(); RD_A(0);
        if (t + 1 < T) SG_A(nxt, t + 1);
        LGKM0; BAR;
        __builtin_amdgcn_s_setprio(1); MM(0); __builtin_amdgcn_s_setprio(0);
        BAR;
        // phase 2
        RD_A(1);
        if (t + 2 < T) SG_B(cur, t + 2, 0);
        LGKM0; BAR;
        __builtin_amdgcn_s_setprio(1); MM(1); __builtin_amdgcn_s_setprio(0);
        BAR;
        // phase 3
        RD_A(2);
        if (t + 2 < T) SG_B(cur, t + 2, 1);
        LGKM0; BAR;
        __builtin_amdgcn_s_setprio(1); MM(2); __builtin_amdgcn_s_setprio(0);
        BAR;
        // phase 4
        RD_A(3);
        if (t + 2 < T) { VMC4; } else { VMC0; }
        LGKM0; BAR;
        __builtin_amdgcn_s_setprio(1); MM(3); __builtin_amdgcn_s_setprio(0);
        BAR;
    }
#undef SG_A
#undef SG_B
#undef RD_B
#undef RD_A
#undef MM
#undef LGKM0
#undef VMC4
#undef VMC0
#undef BAR
}

// ---------------- S pass: S = q k^T (256x256 tiles), P = bf16(exp(S)), rowsum -> lout ----
// Per launch: 2 batches; grid nwg = 512 (bijective XCD swizzle, 512 % 8 == 0).
__global__ __launch_bounds__(512, 2) void s8(const unsigned short* __restrict__ q,
                                             const unsigned short* __restrict__ k,
                                             float* __restrict__ lout,
                                             unsigned short* __restrict__ P,
                                             int nwg) {
    __shared__ unsigned short As[2][256][64], Bs[2][256][64];  // 128 KiB
    int wk = (int)(blockIdx.x & 7) * (nwg >> 3) + (int)(blockIdx.x >> 3);
    int z = wk >> 8, rem = wk & 255;
    int m0 = (rem >> 4) << 8, n0 = (rem & 15) << 8;
    const unsigned short* A = q + (size_t)z * 2097152 + (size_t)m0 * 512;
    const unsigned short* B = k + (size_t)z * 2097152 + (size_t)n0 * 512;
    f32x4 acc[8][4] = {};
    mm8_core(A, 512, B, 512, 8, As, Bs, acc);
    unsigned short* Pz = P + (size_t)z * 16777216;
    float* lz = lout + z * 4096;
    int tid = threadIdx.x, w = tid >> 6, l = tid & 63;
    int wr = w >> 2, wc = w & 3, lr = l & 15, lq4 = (l >> 4) * 4;
#pragma unroll
    for (int mi = 0; mi < 8; ++mi) {
        int rowl = wr * 128 + mi * 16 + lq4;
#pragma unroll
        for (int r = 0; r < 4; ++r) {
            float s = 0.f;
#pragma unroll
            for (int nj = 0; nj < 4; ++nj) {
                float e = __expf(acc[mi][nj][r]);
                s += e;
                Pz[(size_t)(m0 + rowl + r) * 4096 + n0 + wc * 64 + nj * 16 + lr] = f2bf(e);
            }
            s += __shfl_xor(s, 1); s += __shfl_xor(s, 2);
            s += __shfl_xor(s, 4); s += __shfl_xor(s, 8);
            if (lr == 0) atomicAdd(&lz[m0 + rowl + r], s);
        }
    }
}

// ---------------- PV pass: split-K=2, 256x256 tiles -> bf16 partials ----------------
// partial[s][z][m][n] = sum_{k in half s} P[z][m][k] * vt[n][(zofs+z)*4096 + k]
// P batches 0,1 at P0 (+z*16M), batches 2,3 at P1. Partials into dead qb/kb regions.
__global__ __launch_bounds__(512, 2) void pv8(const unsigned short* __restrict__ P0,
                                              const unsigned short* __restrict__ P1,
                                              const unsigned short* __restrict__ vt,
                                              unsigned short* __restrict__ part0,
                                              unsigned short* __restrict__ part1,
                                              int zofs, int nwg) {
    __shared__ unsigned short As[2][256][64], Bs[2][256][64];  // 128 KiB
    int wk = (int)(blockIdx.x & 7) * (nwg >> 3) + (int)(blockIdx.x >> 3);
    int half = nwg >> 1;
    int s = (wk >= half) ? 1 : 0;
    int rem = wk - s * half;
    int z = rem >> 5, t2 = rem & 31;                    // 32 tiles/batch: 16 m x 2 n
    int m0 = (t2 >> 1) << 8, n0 = (t2 & 1) << 8;
    const unsigned short* Pz = (z < 2) ? P0 + (size_t)z * 16777216
                                       : P1 + (size_t)(z - 2) * 16777216;
    const unsigned short* A = Pz + (size_t)m0 * 4096 + (size_t)s * 2048;
    const unsigned short* B = vt + (size_t)n0 * 32768 + (size_t)(zofs + z) * 4096 + (size_t)s * 2048;
    f32x4 acc[8][4] = {};
    mm8_core(A, 4096, B, 32768, 32, As, Bs, acc);
    unsigned short* pp = (s ? part1 : part0) + (size_t)z * 2097152 + (size_t)m0 * 512 + n0;
    int tid = threadIdx.x, w = tid >> 6, l = tid & 63;
    int wr = w >> 2, wc = w & 3, lr = l & 15, lq4 = (l >> 4) * 4;
#pragma unroll
    for (int mi = 0; mi < 8; ++mi)
#pragma unroll
        for (int nj = 0; nj < 4; ++nj)
#pragma unroll
            for (int r = 0; r < 4; ++r)
                pp[(size_t)(wr * 128 + mi * 16 + lq4 + r) * 512 + wc * 64 + nj * 16 + lr] = f2bf(acc[mi][nj][r]);
}

// ---------------- combine split-K partials: o = bf16(p0 + p1) ----------------
__global__ __launch_bounds__(256) void addcvt(const unsigned short* __restrict__ p0,
                                              const unsigned short* __restrict__ p1,
                                              unsigned short* __restrict__ o) {
    size_t i = ((size_t)blockIdx.x * 256 + threadIdx.x) * 8;
    short8 a = *(const short8*)(p0 + i), b = *(const short8*)(p1 + i);
    short8 r;
#pragma unroll
    for (int j = 0; j < 8; ++j)
        r[j] = (short)f2bf(bf2f((unsigned short)a[j]) + bf2f((unsigned short)b[j]));
    *(short8*)(o + i) = r;
}

extern "C" void kernel_launch(void* const* d_in, const int* in_sizes, int n_in,
                              void* d_out, int out_size, void* d_ws, size_t ws_size,
                              hipStream_t stream) {
    const float* x     = (const float*)d_in[0];
    const float* gamma = (const float*)d_in[1];
    const float* beta  = (const float*)d_in[2];
    const float* wq = (const float*)d_in[3];  const float* bq = (const float*)d_in[4];
    const float* wk = (const float*)d_in[5];  const float* bk = (const float*)d_in[6];
    const float* wv = (const float*)d_in[7];  const float* bv = (const float*)d_in[8];
    const float* wo = (const float*)d_in[9];  const float* bo = (const float*)d_in[10];

    // ---- base workspace layout (proven, ends at 136,448,000 B) ----
    char* wsp = (char*)d_ws;
    float* stats        = (float*)wsp;                    //   2 KB
    unsigned short* wqb = (unsigned short*)(wsp + 2048);  // 512 KB each
    unsigned short* wkb = wqb + 262144;
    unsigned short* wvb = wkb + 262144;
    unsigned short* wob = wvb + 262144;
    unsigned short* h   = wob + 262144;                   // 32 MB [B*HW, C] bf16
    unsigned short* qb  = h  + 16777216;                  // 32 MB
    unsigned short* kb  = qb + 16777216;                  // 32 MB
    unsigned short* vtb = kb + 16777216;                  // 32 MB [C, B*HW] bf16
    float* lbuf         = (float*)(vtb + 16777216);       // 128 KB softmax denoms
    unsigned short* Pw  = (unsigned short*)(lbuf + 32768);// mid path: +64 MB, ends 203.6 MB
    unsigned short* Pd  = (unsigned short*)d_out;         // 64 MB: 2 batches of P
    unsigned short* ob  = h;                              // alias: h dead after vT GEMM

    // mid path needs 203,556,864 B total
    const bool mid = ws_size >= 204000000ull;

    gn_stats<<<256, 256, 0, stream>>>(x, stats);
    wcvt<<<256, 256, 0, stream>>>(wq, wqb);
    wcvt<<<256, 256, 0, stream>>>(wk, wkb);
    wcvt<<<256, 256, 0, stream>>>(wv, wvb);
    wcvt<<<256, 256, 0, stream>>>(wo, wob);
    gn_apply<<<dim3(64, 8, 8), 256, 0, stream>>>(x, stats, gamma, beta, h);
    zero_l<<<32, 256, 0, stream>>>(lbuf);

    // q = alpha*(h wq^T + bq), k = h wk^T + bk  : [32768 x 512]
    gemm_bt<<<dim3(4, 256), 256, 0, stream>>>(h, 512, 0, wqb, 512, 0, bq, nullptr, nullptr,
                                              qb, 512, 0, 512, 0, ALPHA);
    gemm_bt<<<dim3(4, 256), 256, 0, stream>>>(h, 512, 0, wkb, 512, 0, bk, nullptr, nullptr,
                                              kb, 512, 0, 512, 0, 1.0f);
    // vT[c, pos] = wv h^T + bv : [512 x 32768]
    gemm_bt<<<dim3(256, 4), 256, 0, stream>>>(wvb, 512, 0, h, 512, 0, bv, nullptr, nullptr,
                                              vtb, 32768, 0, 512, 1, 1.0f);

    const long QS = (long)4096 * 512;   // per-batch q/k/o stride (elements)
    if (mid) {
        // ---- 2 chunks x 4 batches: P in d_out (2) + ws tail (2) ----
        // After each chunk's S-passes, that chunk's qb/kb regions are dead ->
        // reuse as split-K partial buffers (16 MB each), then addcvt -> ob.
        for (int c = 0; c < 2; ++c) {
            size_t z0 = (size_t)c * 4;
            s8<<<512, 512, 0, stream>>>(qb + z0 * QS, kb + z0 * QS,
                                        lbuf + z0 * 4096, Pd, 512);
            s8<<<512, 512, 0, stream>>>(qb + (z0 + 2) * QS, kb + (z0 + 2) * QS,
                                        lbuf + (z0 + 2) * 4096, Pw, 512);
            pv8<<<256, 512, 0, stream>>>(Pd, Pw, vtb,
                                         qb + z0 * QS, kb + z0 * QS, (int)z0, 256);
            addcvt<<<4096, 256, 0, stream>>>(qb + z0 * QS, kb + z0 * QS, ob + z0 * QS);
        }
    } else {
        // ---- 4 chunks x 2 batches: P in d_out only ----
        for (int c = 0; c < 4; ++c) {
            size_t z0 = (size_t)c * 2;
            s8<<<512, 512, 0, stream>>>(qb + z0 * QS, kb + z0 * QS,
                                        lbuf + z0 * 4096, Pd, 512);
            pv8<<<128, 512, 0, stream>>>(Pd, Pd, vtb,
                                         qb + z0 * QS, kb + z0 * QS, (int)z0, 128);
            addcvt<<<2048, 256, 0, stream>>>(qb + z0 * QS, kb + z0 * QS, ob + z0 * QS);
        }
    }
    // out[b,c,hw] = (wo o_unnorm^T)/l + bo + x   (overwrites all of d_out)
    gemm_bt<<<dim3(256, 4), 256, 0, stream>>>(wob, 512, 0, ob, 512, 0, bo, x, lbuf,
                                              d_out, 0, 0, 512, 2, 1.0f);
}

// Round 6
// 779.963 us; speedup vs baseline: 1.1543x; 1.0293x over previous
//
#include <hip/hip_runtime.h>
#include <hip/hip_bf16.h>

// B=8, C=512, G=32, HW=4096. All matrix dims are multiples of 128 -> no guards.
typedef __attribute__((ext_vector_type(8))) short short8;
typedef __attribute__((ext_vector_type(4))) float f32x4;

#define ALPHA 0.044194173824159216f

// global_load_lds helpers: LDS dest is wave-uniform base + lane*16 (linear).
#define GLO(p) (const __attribute__((address_space(1))) void*)(p)
#define LDSP(p) (__attribute__((address_space(3))) void*)(p)

__device__ __forceinline__ unsigned short f2bf(float f) {
    union { float f; unsigned int u; } c; c.f = f;
    unsigned int u = c.u;
    return (unsigned short)((u + 0x7FFFu + ((u >> 16) & 1u)) >> 16);
}

__device__ __forceinline__ float bf2f(unsigned short s) {
    union { unsigned int u; float f; } c; c.u = ((unsigned int)s) << 16;
    return c.f;
}

// ---------------- GroupNorm stats: one block per (b,g), 16ch x 4096 contiguous ----
__global__ __launch_bounds__(256) void gn_stats(const float* __restrict__ x,
                                                float* __restrict__ stats) {
    int blk = blockIdx.x;  // b*32 + g
    const float4* src = (const float4*)(x + (size_t)blk * 65536);
    float s = 0.f, sq = 0.f;
    for (int i = threadIdx.x; i < 16384; i += 256) {
        float4 v = src[i];
        s  += v.x + v.y + v.z + v.w;
        sq += v.x*v.x + v.y*v.y + v.z*v.z + v.w*v.w;
    }
    for (int off = 32; off; off >>= 1) {
        s  += __shfl_down(s, off);
        sq += __shfl_down(sq, off);
    }
    __shared__ float ss[4], ssq[4];
    int wid = threadIdx.x >> 6;
    if ((threadIdx.x & 63) == 0) { ss[wid] = s; ssq[wid] = sq; }
    __syncthreads();
    if (threadIdx.x == 0) {
        float S = ss[0]+ss[1]+ss[2]+ss[3], Q = ssq[0]+ssq[1]+ssq[2]+ssq[3];
        float mu = S * (1.f/65536.f);
        float var = Q * (1.f/65536.f) - mu*mu;
        stats[blk] = mu;
        stats[256 + blk] = rsqrtf(var + 1e-6f);
    }
}

// ---------------- weight fp32 -> bf16 ----------------
__global__ __launch_bounds__(256) void wcvt(const float* __restrict__ s,
                                            unsigned short* __restrict__ d) {
    int i = blockIdx.x * 1024 + threadIdx.x * 4;
    float4 v = *(const float4*)(s + i);
    ushort4 o = make_ushort4(f2bf(v.x), f2bf(v.y), f2bf(v.z), f2bf(v.w));
    *(ushort4*)(d + i) = o;
}

// ---------------- zero the softmax-denominator accumulator ----------------
__global__ __launch_bounds__(256) void zero_l(float* __restrict__ l) {
    ((float4*)l)[blockIdx.x * 256 + threadIdx.x] = make_float4(0.f, 0.f, 0.f, 0.f);
}

// ---------------- invert softmax denominators in place: l -> 1/l ----------------
__global__ __launch_bounds__(256) void recip(float* __restrict__ l) {
    int i = blockIdx.x * 256 + threadIdx.x;
    float4 v = ((const float4*)l)[i];
    ((float4*)l)[i] = make_float4(1.f / v.x, 1.f / v.y, 1.f / v.z, 1.f / v.w);
}

// ------- GN apply + transpose: x[b][c][hw] fp32 -> h[(b*4096+hw)][c] bf16 -------
__global__ __launch_bounds__(256) void gn_apply(const float* __restrict__ x,
                                                const float* __restrict__ stats,
                                                const float* __restrict__ gamma,
                                                const float* __restrict__ beta,
                                                unsigned short* __restrict__ h) {
    __shared__ unsigned short t[64][72];  // [hw_local][c_local], pad 72
    int b = blockIdx.z, c0 = blockIdx.y * 64, hw0 = blockIdx.x * 64;
    int tid = threadIdx.x;
#pragma unroll
    for (int rep = 0; rep < 4; ++rep) {
        int lin = rep * 256 + tid;         // 1024 = 64 c-rows x 16 float4
        int row = lin >> 4;                // c_local
        int c4  = lin & 15;                // float4 idx along hw
        int c   = c0 + row;
        const float4* src = (const float4*)(x + ((size_t)(b*512 + c) << 12) + hw0);
        float4 v = src[c4];
        int sidx = b*32 + (c >> 4);
        float mu = stats[sidx], rs = stats[256 + sidx];
        float ga = gamma[c] * rs, be = beta[c] - mu * ga;
        t[c4*4+0][row] = f2bf(v.x * ga + be);
        t[c4*4+1][row] = f2bf(v.y * ga + be);
        t[c4*4+2][row] = f2bf(v.z * ga + be);
        t[c4*4+3][row] = f2bf(v.w * ga + be);
    }
    __syncthreads();
#pragma unroll
    for (int rep = 0; rep < 2; ++rep) {
        int lin = rep * 256 + tid;         // 512 = 64 hw-rows x 8 groups
        int row = lin >> 3;                // hw_local
        int u8  = lin & 7;
        unsigned short* dst = h + (((size_t)(b*4096 + hw0 + row)) << 9) + c0 + u8*8;
        *(short8*)dst = *(const short8*)&t[row][u8*8];
    }
}

// ---------------- universal 128x128 bf16 MFMA GEMM, BK=64 (reg-staged, proven) ----
// C[m,n] = sum_k A[m,k] * B[n,k]
// mode 0: out bf16, out[m*ldo+n] = bf16((acc + bias[n]) * scale)          (q/k proj)
// mode 1: out bf16, out[m*ldo+n] = bf16(acc + bias[m])                    (vT proj)
// mode 2: out fp32 d_out[b][m][hw], n = b*4096+hw:
//           acc * rlvec[n] + bias[m] + resid   (rlvec holds 1/l)          (o-proj)
//   Epilogue is latency-critical: batch all 16 resid loads per i-block into
//   registers (one drain), multiply by the precomputed reciprocal (no div chain).
__global__ __launch_bounds__(256, 2) void gemm_bt(const unsigned short* __restrict__ A,
                                                  int lda, long aZs,
                                                  const unsigned short* __restrict__ B,
                                                  int ldb, long bZs,
                                                  const float* __restrict__ bias,
                                                  const float* __restrict__ resid,
                                                  const float* __restrict__ lvec,
                                                  void* __restrict__ out,
                                                  long ldo, long oZs,
                                                  int K, int mode, float scale) {
    __shared__ unsigned short As[128][72], Bs[128][72];  // 64-wide K-slab, pad 72
    int z = blockIdx.z;
    A += (size_t)z * aZs;
    B += (size_t)z * bZs;
    unsigned short* outu = (unsigned short*)out + (size_t)z * oZs;
    int m0 = blockIdx.y * 128, n0 = blockIdx.x * 128;
    int tid = threadIdx.x, w = tid >> 6, l = tid & 63;
    int lr = l & 15, lq = l >> 4, lk = lq * 8;
    int rbase = (w >> 1) * 64, cbase = (w & 1) * 64;
    f32x4 acc[4][4] = {};
    for (int k0 = 0; k0 < K; k0 += 64) {
        __syncthreads();
#pragma unroll
        for (int p = 0; p < 4; ++p) {
            int lin = p * 256 + tid;           // 1024 = 128 rows x 8 short8
            int r = lin >> 3, qq = lin & 7;
            *(short8*)&As[r][qq*8] = *(const short8*)(A + (size_t)(m0 + r)*lda + k0 + qq*8);
            *(short8*)&Bs[r][qq*8] = *(const short8*)(B + (size_t)(n0 + r)*ldb + k0 + qq*8);
        }
        __syncthreads();
        short8 af[4][2], bfv[4][2];
#pragma unroll
        for (int i = 0; i < 4; ++i)
#pragma unroll
            for (int ks = 0; ks < 2; ++ks) {
                af[i][ks]  = *(const short8*)&As[rbase + i*16 + lr][ks*32 + lk];
                bfv[i][ks] = *(const short8*)&Bs[cbase + i*16 + lr][ks*32 + lk];
            }
#pragma unroll
        for (int ks = 0; ks < 2; ++ks)
#pragma unroll
            for (int i = 0; i < 4; ++i)
#pragma unroll
                for (int j = 0; j < 4; ++j)
                    acc[i][j] = __builtin_amdgcn_mfma_f32_16x16x32_bf16(af[i][ks], bfv[j][ks], acc[i][j], 0, 0, 0);
    }
    int lq4 = lq * 4;
    if (mode == 2) {
        // reciprocal denominators: one load per output column group, hoisted
        float rlv[4];
#pragma unroll
        for (int j = 0; j < 4; ++j) rlv[j] = lvec[n0 + cbase + j*16 + lr];
        float* outf = (float*)out;
#pragma unroll
        for (int i = 0; i < 4; ++i) {
            int rowg = m0 + rbase + i*16 + lq4;
            float4 bq4 = *(const float4*)(bias + rowg);   // rowg % 4 == 0
            float bb[4] = {bq4.x, bq4.y, bq4.z, bq4.w};
            size_t ad[16];
            float lres[16];
#pragma unroll
            for (int j = 0; j < 4; ++j) {
                int colg = n0 + cbase + j*16 + lr;
                size_t base = ((size_t)(colg >> 12)) * 2097152 + (size_t)(colg & 4095);
#pragma unroll
                for (int r = 0; r < 4; ++r) {
                    ad[j*4+r] = base + (size_t)(rowg + r) * 4096;
                    lres[j*4+r] = resid[ad[j*4+r]];
                }
            }
#pragma unroll
            for (int j = 0; j < 4; ++j)
#pragma unroll
                for (int r = 0; r < 4; ++r)
                    outf[ad[j*4+r]] = acc[i][j][r] * rlv[j] + bb[r] + lres[j*4+r];
        }
        return;
    }
#pragma unroll
    for (int i = 0; i < 4; ++i) {
        int rowg = m0 + rbase + i*16 + lq4;
#pragma unroll
        for (int j = 0; j < 4; ++j) {
            int colg = n0 + cbase + j*16 + lr;
#pragma unroll
            for (int r = 0; r < 4; ++r) {
                float v = acc[i][j][r];
                int rr = rowg + r;
                if (mode == 0) {
                    outu[(size_t)rr * ldo + colg] = f2bf((v + bias[colg]) * scale);
                } else {
                    outu[(size_t)rr * ldo + colg] = f2bf(v + bias[rr]);
                }
            }
        }
    }
}

// =====================================================================
// 8-phase-style 256x256 MFMA core (T1+T2+T3+T4+T5), BK=64, 512 thr, 8 waves (2Mx4N)
// LDS 128 KiB: As/Bs [2][256][64] linear, both-sides XOR swizzle (verified 0-conflict
// in R2/R3 PV): source col pre-permuted ((l&7)^(l>>3))*8; read addr ^ (lr&7)<<4.
// Staging ledger (2 buffers, hazard-audited):
//   phase 1 of tile t: read all B-frags + A m-pair0; issue A(t+1) -> buf^1.  [4 loads]
//   phase 2: read A m-pair1; issue B-half0(t+2) -> buf cur (B read in ph1).  [2 loads]
//   phase 3: read A m-pair2; issue B-half1(t+2).                             [2 loads]
//   phase 4: read A m-pair3; vmcnt(4): drains B(t+1)+A(t+1), leaves B(t+2)
//     in flight. NEVER vmcnt(0) in steady state (T4).
// Each phase: lgkmcnt(0)+sched_barrier (rule #18), s_barrier, setprio(1),
// 16 MFMA, setprio(0), s_barrier.
// =====================================================================
__device__ __forceinline__ void mm8_core(const unsigned short* __restrict__ A, int lda,
                                         const unsigned short* __restrict__ B, int ldb,
                                         int T,
                                         unsigned short (*As)[256][64],
                                         unsigned short (*Bs)[256][64],
                                         f32x4 acc[8][4]) {
    int tid = threadIdx.x, w = tid >> 6, l = tid & 63;
    int wr = w >> 2, wc = w & 3;
    int lr = l & 15, lq = l >> 4;
    int rsub = l >> 3, colp = ((l & 7) ^ rsub) << 3;   // pre-permuted source col
    int sw = (lr & 7) << 4;                             // read-side XOR
    int aw = w * 8;                                     // wave row offset in 64-row span

#define SG_A(buf, t_) { \
    const unsigned short* ap = A + (size_t)(t_) * 64; \
    __builtin_amdgcn_global_load_lds(GLO(ap + (size_t)(aw + rsub) * lda + colp),        LDSP(&As[buf][aw][0]), 16, 0, 0); \
    __builtin_amdgcn_global_load_lds(GLO(ap + (size_t)(64 + aw + rsub) * lda + colp),   LDSP(&As[buf][64 + aw][0]), 16, 0, 0); \
    __builtin_amdgcn_global_load_lds(GLO(ap + (size_t)(128 + aw + rsub) * lda + colp),  LDSP(&As[buf][128 + aw][0]), 16, 0, 0); \
    __builtin_amdgcn_global_load_lds(GLO(ap + (size_t)(192 + aw + rsub) * lda + colp),  LDSP(&As[buf][192 + aw][0]), 16, 0, 0); }
#define SG_B(buf, t_, h_) { \
    const unsigned short* bp = B + (size_t)(t_) * 64; int rb = (h_) * 128 + aw; \
    __builtin_amdgcn_global_load_lds(GLO(bp + (size_t)(rb + rsub) * ldb + colp),       LDSP(&Bs[buf][rb][0]), 16, 0, 0); \
    __builtin_amdgcn_global_load_lds(GLO(bp + (size_t)(rb + 64 + rsub) * ldb + colp),  LDSP(&Bs[buf][rb + 64][0]), 16, 0, 0); }
#define RD_B() { \
    const char* bsb = (const char*)Bs[cur]; \
    _Pragma("unroll") for (int nj = 0; nj < 4; ++nj) \
    _Pragma("unroll") for (int ks = 0; ks < 2; ++ks) { \
        int row = wc * 64 + nj * 16 + lr; \
        bf[nj][ks] = *(const short8*)(bsb + (((row << 7) + (ks << 6) + (lq << 4)) ^ sw)); } }
#define RD_A(p_) { \
    const char* asb = (const char*)As[cur]; \
    _Pragma("unroll") for (int i = 0; i < 2; ++i) \
    _Pragma("unroll") for (int ks = 0; ks < 2; ++ks) { \
        int row = wr * 128 + ((p_) * 2 + i) * 16 + lr; \
        af[i][ks] = *(const short8*)(asb + (((row << 7) + (ks << 6) + (lq << 4)) ^ sw)); } }
#define MM(p_) { \
    _Pragma("unroll") for (int ks = 0; ks < 2; ++ks) \
    _Pragma("unroll") for (int i = 0; i < 2; ++i) \
    _Pragma("unroll") for (int nj = 0; nj < 4; ++nj) \
        acc[(p_) * 2 + i][nj] = __builtin_amdgcn_mfma_f32_16x16x32_bf16(af[i][ks], bf[nj][ks], acc[(p_) * 2 + i][nj], 0, 0, 0); }
#define LGKM0 { asm volatile("s_waitcnt lgkmcnt(0)" ::: "memory"); __builtin_amdgcn_sched_barrier(0); }
#define VMC4 { asm volatile("s_waitcnt vmcnt(4)" ::: "memory"); __builtin_amdgcn_sched_barrier(0); }
#define VMC0 { asm volatile("s_waitcnt vmcnt(0)" ::: "memory"); __builtin_amdgcn_sched_barrier(0); }
#define BAR __builtin_amdgcn_s_barrier()

    // prologue: tile 0 (A+B) -> buf0; B(1) -> buf1; drain tile 0, keep B(1) in flight
    SG_A(0, 0); SG_B(0, 0, 0); SG_B(0, 0, 1);
    if (T > 1) { SG_B(1, 1, 0); SG_B(1, 1, 1); VMC4; } else { VMC0; }
    BAR;
    for (int t = 0; t < T; ++t) {
        int cur = t & 1, nxt = cur ^ 1;
        short8 bf[4][2], af[2][2];
        // phase 1
        RD_B(); RD_A(0);
        if (t + 1 < T) SG_A(nxt, t + 1);
        LGKM0; BAR;
        __builtin_amdgcn_s_setprio(1); MM(0); __builtin_amdgcn_s_setprio(0);
        BAR;
        // phase 2
        RD_A(1);
        if (t + 2 < T) SG_B(cur, t + 2, 0);
        LGKM0; BAR;
        __builtin_amdgcn_s_setprio(1); MM(1); __builtin_amdgcn_s_setprio(0);
        BAR;
        // phase 3
        RD_A(2);
        if (t + 2 < T) SG_B(cur, t + 2, 1);
        LGKM0; BAR;
        __builtin_amdgcn_s_setprio(1); MM(2); __builtin_amdgcn_s_setprio(0);
        BAR;
        // phase 4
        RD_A(3);
        if (t + 2 < T) { VMC4; } else { VMC0; }
        LGKM0; BAR;
        __builtin_amdgcn_s_setprio(1); MM(3); __builtin_amdgcn_s_setprio(0);
        BAR;
    }
#undef SG_A
#undef SG_B
#undef RD_B
#undef RD_A
#undef MM
#undef LGKM0
#undef VMC4
#undef VMC0
#undef BAR
}

// ---------------- S pass: S = q k^T (256x256 tiles), P = bf16(exp(S)), rowsum -> lout ----
// Per launch: 2 batches; grid nwg = 512 (bijective XCD swizzle, 512 % 8 == 0).
__global__ __launch_bounds__(512, 2) void s8(const unsigned short* __restrict__ q,
                                             const unsigned short* __restrict__ k,
                                             float* __restrict__ lout,
                                             unsigned short* __restrict__ P,
                                             int nwg) {
    __shared__ unsigned short As[2][256][64], Bs[2][256][64];  // 128 KiB
    int wk = (int)(blockIdx.x & 7) * (nwg >> 3) + (int)(blockIdx.x >> 3);
    int z = wk >> 8, rem = wk & 255;
    int m0 = (rem >> 4) << 8, n0 = (rem & 15) << 8;
    const unsigned short* A = q + (size_t)z * 2097152 + (size_t)m0 * 512;
    const unsigned short* B = k + (size_t)z * 2097152 + (size_t)n0 * 512;
    f32x4 acc[8][4] = {};
    mm8_core(A, 512, B, 512, 8, As, Bs, acc);
    unsigned short* Pz = P + (size_t)z * 16777216;
    float* lz = lout + z * 4096;
    int tid = threadIdx.x, w = tid >> 6, l = tid & 63;
    int wr = w >> 2, wc = w & 3, lr = l & 15, lq4 = (l >> 4) * 4;
#pragma unroll
    for (int mi = 0; mi < 8; ++mi) {
        int rowl = wr * 128 + mi * 16 + lq4;
#pragma unroll
        for (int r = 0; r < 4; ++r) {
            float s = 0.f;
#pragma unroll
            for (int nj = 0; nj < 4; ++nj) {
                float e = __expf(acc[mi][nj][r]);
                s += e;
                Pz[(size_t)(m0 + rowl + r) * 4096 + n0 + wc * 64 + nj * 16 + lr] = f2bf(e);
            }
            s += __shfl_xor(s, 1); s += __shfl_xor(s, 2);
            s += __shfl_xor(s, 4); s += __shfl_xor(s, 8);
            if (lr == 0) atomicAdd(&lz[m0 + rowl + r], s);
        }
    }
}

// ---------------- PV pass: split-K=2, 256x256 tiles -> bf16 partials ----------------
// partial[s][z][m][n] = sum_{k in half s} P[z][m][k] * vt[n][(zofs+z)*4096 + k]
// P batches 0,1 at P0 (+z*16M), batches 2,3 at P1. Partials into dead qb/kb regions.
__global__ __launch_bounds__(512, 2) void pv8(const unsigned short* __restrict__ P0,
                                              const unsigned short* __restrict__ P1,
                                              const unsigned short* __restrict__ vt,
                                              unsigned short* __restrict__ part0,
                                              unsigned short* __restrict__ part1,
                                              int zofs, int nwg) {
    __shared__ unsigned short As[2][256][64], Bs[2][256][64];  // 128 KiB
    int wk = (int)(blockIdx.x & 7) * (nwg >> 3) + (int)(blockIdx.x >> 3);
    int half = nwg >> 1;
    int s = (wk >= half) ? 1 : 0;
    int rem = wk - s * half;
    int z = rem >> 5, t2 = rem & 31;                    // 32 tiles/batch: 16 m x 2 n
    int m0 = (t2 >> 1) << 8, n0 = (t2 & 1) << 8;
    const unsigned short* Pz = (z < 2) ? P0 + (size_t)z * 16777216
                                       : P1 + (size_t)(z - 2) * 16777216;
    const unsigned short* A = Pz + (size_t)m0 * 4096 + (size_t)s * 2048;
    const unsigned short* B = vt + (size_t)n0 * 32768 + (size_t)(zofs + z) * 4096 + (size_t)s * 2048;
    f32x4 acc[8][4] = {};
    mm8_core(A, 4096, B, 32768, 32, As, Bs, acc);
    unsigned short* pp = (s ? part1 : part0) + (size_t)z * 2097152 + (size_t)m0 * 512 + n0;
    int tid = threadIdx.x, w = tid >> 6, l = tid & 63;
    int wr = w >> 2, wc = w & 3, lr = l & 15, lq4 = (l >> 4) * 4;
#pragma unroll
    for (int mi = 0; mi < 8; ++mi)
#pragma unroll
        for (int nj = 0; nj < 4; ++nj)
#pragma unroll
            for (int r = 0; r < 4; ++r)
                pp[(size_t)(wr * 128 + mi * 16 + lq4 + r) * 512 + wc * 64 + nj * 16 + lr] = f2bf(acc[mi][nj][r]);
}

// ---------------- combine split-K partials: o = bf16(p0 + p1) ----------------
__global__ __launch_bounds__(256) void addcvt(const unsigned short* __restrict__ p0,
                                              const unsigned short* __restrict__ p1,
                                              unsigned short* __restrict__ o) {
    size_t i = ((size_t)blockIdx.x * 256 + threadIdx.x) * 8;
    short8 a = *(const short8*)(p0 + i), b = *(const short8*)(p1 + i);
    short8 r;
#pragma unroll
    for (int j = 0; j < 8; ++j)
        r[j] = (short)f2bf(bf2f((unsigned short)a[j]) + bf2f((unsigned short)b[j]));
    *(short8*)(o + i) = r;
}

extern "C" void kernel_launch(void* const* d_in, const int* in_sizes, int n_in,
                              void* d_out, int out_size, void* d_ws, size_t ws_size,
                              hipStream_t stream) {
    const float* x     = (const float*)d_in[0];
    const float* gamma = (const float*)d_in[1];
    const float* beta  = (const float*)d_in[2];
    const float* wq = (const float*)d_in[3];  const float* bq = (const float*)d_in[4];
    const float* wk = (const float*)d_in[5];  const float* bk = (const float*)d_in[6];
    const float* wv = (const float*)d_in[7];  const float* bv = (const float*)d_in[8];
    const float* wo = (const float*)d_in[9];  const float* bo = (const float*)d_in[10];

    // ---- base workspace layout (proven, ends at 136,448,000 B) ----
    char* wsp = (char*)d_ws;
    float* stats        = (float*)wsp;                    //   2 KB
    unsigned short* wqb = (unsigned short*)(wsp + 2048);  // 512 KB each
    unsigned short* wkb = wqb + 262144;
    unsigned short* wvb = wkb + 262144;
    unsigned short* wob = wvb + 262144;
    unsigned short* h   = wob + 262144;                   // 32 MB [B*HW, C] bf16
    unsigned short* qb  = h  + 16777216;                  // 32 MB
    unsigned short* kb  = qb + 16777216;                  // 32 MB
    unsigned short* vtb = kb + 16777216;                  // 32 MB [C, B*HW] bf16
    float* lbuf         = (float*)(vtb + 16777216);       // 128 KB softmax denoms
    unsigned short* Pw  = (unsigned short*)(lbuf + 32768);// mid path: +64 MB, ends 203.6 MB
    unsigned short* Pd  = (unsigned short*)d_out;         // 64 MB: 2 batches of P
    unsigned short* ob  = h;                              // alias: h dead after vT GEMM

    // mid path needs 203,556,864 B total
    const bool mid = ws_size >= 204000000ull;

    gn_stats<<<256, 256, 0, stream>>>(x, stats);
    wcvt<<<256, 256, 0, stream>>>(wq, wqb);
    wcvt<<<256, 256, 0, stream>>>(wk, wkb);
    wcvt<<<256, 256, 0, stream>>>(wv, wvb);
    wcvt<<<256, 256, 0, stream>>>(wo, wob);
    gn_apply<<<dim3(64, 8, 8), 256, 0, stream>>>(x, stats, gamma, beta, h);
    zero_l<<<32, 256, 0, stream>>>(lbuf);

    // q = alpha*(h wq^T + bq), k = h wk^T + bk  : [32768 x 512]
    gemm_bt<<<dim3(4, 256), 256, 0, stream>>>(h, 512, 0, wqb, 512, 0, bq, nullptr, nullptr,
                                              qb, 512, 0, 512, 0, ALPHA);
    gemm_bt<<<dim3(4, 256), 256, 0, stream>>>(h, 512, 0, wkb, 512, 0, bk, nullptr, nullptr,
                                              kb, 512, 0, 512, 0, 1.0f);
    // vT[c, pos] = wv h^T + bv : [512 x 32768]
    gemm_bt<<<dim3(256, 4), 256, 0, stream>>>(wvb, 512, 0, h, 512, 0, bv, nullptr, nullptr,
                                              vtb, 32768, 0, 512, 1, 1.0f);

    const long QS = (long)4096 * 512;   // per-batch q/k/o stride (elements)
    if (mid) {
        // ---- 2 chunks x 4 batches: P in d_out (2) + ws tail (2) ----
        // After each chunk's S-passes, that chunk's qb/kb regions are dead ->
        // reuse as split-K partial buffers (16 MB each), then addcvt -> ob.
        for (int c = 0; c < 2; ++c) {
            size_t z0 = (size_t)c * 4;
            s8<<<512, 512, 0, stream>>>(qb + z0 * QS, kb + z0 * QS,
                                        lbuf + z0 * 4096, Pd, 512);
            s8<<<512, 512, 0, stream>>>(qb + (z0 + 2) * QS, kb + (z0 + 2) * QS,
                                        lbuf + (z0 + 2) * 4096, Pw, 512);
            pv8<<<256, 512, 0, stream>>>(Pd, Pw, vtb,
                                         qb + z0 * QS, kb + z0 * QS, (int)z0, 256);
            addcvt<<<4096, 256, 0, stream>>>(qb + z0 * QS, kb + z0 * QS, ob + z0 * QS);
        }
    } else {
        // ---- 4 chunks x 2 batches: P in d_out only ----
        for (int c = 0; c < 4; ++c) {
            size_t z0 = (size_t)c * 2;
            s8<<<512, 512, 0, stream>>>(qb + z0 * QS, kb + z0 * QS,
                                        lbuf + z0 * 4096, Pd, 512);
            pv8<<<128, 512, 0, stream>>>(Pd, Pd, vtb,
                                         qb + z0 * QS, kb + z0 * QS, (int)z0, 128);
            addcvt<<<2048, 256, 0, stream>>>(qb + z0 * QS, kb + z0 * QS, ob + z0 * QS);
        }
    }
    // l -> 1/l (all 8 batches accumulated), then
    // out[b,c,hw] = (wo o_unnorm^T) * (1/l) + bo + x   (overwrites all of d_out)
    recip<<<32, 256, 0, stream>>>(lbuf);
    gemm_bt<<<dim3(256, 4), 256, 0, stream>>>(wob, 512, 0, ob, 512, 0, bo, x, lbuf,
                                              d_out, 0, 0, 512, 2, 1.0f);
}

// Round 7
// 724.574 us; speedup vs baseline: 1.2426x; 1.0764x over previous
//
#include <hip/hip_runtime.h>
#include <hip/hip_bf16.h>

// B=8, C=512, G=32, HW=4096. All matrix dims are multiples of 128 -> no guards.
typedef __attribute__((ext_vector_type(8))) short short8;
typedef __attribute__((ext_vector_type(4))) float f32x4;

#define ALPHA 0.044194173824159216f

// global_load_lds helpers: LDS dest is wave-uniform base + lane*16 (linear).
#define GLO(p) (const __attribute__((address_space(1))) void*)(p)
#define LDSP(p) (__attribute__((address_space(3))) void*)(p)

__device__ __forceinline__ unsigned short f2bf(float f) {
    union { float f; unsigned int u; } c; c.f = f;
    unsigned int u = c.u;
    return (unsigned short)((u + 0x7FFFu + ((u >> 16) & 1u)) >> 16);
}

__device__ __forceinline__ float bf2f(unsigned short s) {
    union { unsigned int u; float f; } c; c.u = ((unsigned int)s) << 16;
    return c.f;
}

// ---------------- GroupNorm stats: one block per (b,g), 16ch x 4096 contiguous ----
__global__ __launch_bounds__(256) void gn_stats(const float* __restrict__ x,
                                                float* __restrict__ stats) {
    int blk = blockIdx.x;  // b*32 + g
    const float4* src = (const float4*)(x + (size_t)blk * 65536);
    float s = 0.f, sq = 0.f;
    for (int i = threadIdx.x; i < 16384; i += 256) {
        float4 v = src[i];
        s  += v.x + v.y + v.z + v.w;
        sq += v.x*v.x + v.y*v.y + v.z*v.z + v.w*v.w;
    }
    for (int off = 32; off; off >>= 1) {
        s  += __shfl_down(s, off);
        sq += __shfl_down(sq, off);
    }
    __shared__ float ss[4], ssq[4];
    int wid = threadIdx.x >> 6;
    if ((threadIdx.x & 63) == 0) { ss[wid] = s; ssq[wid] = sq; }
    __syncthreads();
    if (threadIdx.x == 0) {
        float S = ss[0]+ss[1]+ss[2]+ss[3], Q = ssq[0]+ssq[1]+ssq[2]+ssq[3];
        float mu = S * (1.f/65536.f);
        float var = Q * (1.f/65536.f) - mu*mu;
        stats[blk] = mu;
        stats[256 + blk] = rsqrtf(var + 1e-6f);
    }
}

// ---------------- weight fp32 -> bf16 ----------------
__global__ __launch_bounds__(256) void wcvt(const float* __restrict__ s,
                                            unsigned short* __restrict__ d) {
    int i = blockIdx.x * 1024 + threadIdx.x * 4;
    float4 v = *(const float4*)(s + i);
    ushort4 o = make_ushort4(f2bf(v.x), f2bf(v.y), f2bf(v.z), f2bf(v.w));
    *(ushort4*)(d + i) = o;
}

// ---------------- zero the softmax-denominator accumulator ----------------
__global__ __launch_bounds__(256) void zero_l(float* __restrict__ l) {
    ((float4*)l)[blockIdx.x * 256 + threadIdx.x] = make_float4(0.f, 0.f, 0.f, 0.f);
}

// ---------------- invert softmax denominators in place: l -> 1/l ----------------
__global__ __launch_bounds__(256) void recip(float* __restrict__ l) {
    int i = blockIdx.x * 256 + threadIdx.x;
    float4 v = ((const float4*)l)[i];
    ((float4*)l)[i] = make_float4(1.f / v.x, 1.f / v.y, 1.f / v.z, 1.f / v.w);
}

// ------- GN apply + transpose: x[b][c][hw] fp32 -> h[(b*4096+hw)][c] bf16 -------
__global__ __launch_bounds__(256) void gn_apply(const float* __restrict__ x,
                                                const float* __restrict__ stats,
                                                const float* __restrict__ gamma,
                                                const float* __restrict__ beta,
                                                unsigned short* __restrict__ h) {
    __shared__ unsigned short t[64][72];  // [hw_local][c_local], pad 72
    int b = blockIdx.z, c0 = blockIdx.y * 64, hw0 = blockIdx.x * 64;
    int tid = threadIdx.x;
#pragma unroll
    for (int rep = 0; rep < 4; ++rep) {
        int lin = rep * 256 + tid;         // 1024 = 64 c-rows x 16 float4
        int row = lin >> 4;                // c_local
        int c4  = lin & 15;                // float4 idx along hw
        int c   = c0 + row;
        const float4* src = (const float4*)(x + ((size_t)(b*512 + c) << 12) + hw0);
        float4 v = src[c4];
        int sidx = b*32 + (c >> 4);
        float mu = stats[sidx], rs = stats[256 + sidx];
        float ga = gamma[c] * rs, be = beta[c] - mu * ga;
        t[c4*4+0][row] = f2bf(v.x * ga + be);
        t[c4*4+1][row] = f2bf(v.y * ga + be);
        t[c4*4+2][row] = f2bf(v.z * ga + be);
        t[c4*4+3][row] = f2bf(v.w * ga + be);
    }
    __syncthreads();
#pragma unroll
    for (int rep = 0; rep < 2; ++rep) {
        int lin = rep * 256 + tid;         // 512 = 64 hw-rows x 8 groups
        int row = lin >> 3;                // hw_local
        int u8  = lin & 7;
        unsigned short* dst = h + (((size_t)(b*4096 + hw0 + row)) << 9) + c0 + u8*8;
        *(short8*)dst = *(const short8*)&t[row][u8*8];
    }
}

// ---------------- universal 128x128 bf16 MFMA GEMM, BK=64 (reg-staged, proven) ----
// C[m,n] = sum_k A[m,k] * B[n,k]
// mode 0: out bf16, out[m*ldo+n] = bf16((acc + bias[n]) * scale)          (q/k proj)
// mode 1: out bf16, out[m*ldo+n] = bf16(acc + bias[m])                    (vT proj)
// mode 2: out fp32 d_out[b][m][hw], n = b*4096+hw:
//           acc * rlvec[n] + bias[m] + resid   (rlvec holds 1/l)          (o-proj)
//   Epilogue is latency-critical: batch all 16 resid loads per i-block into
//   registers (one drain), multiply by the precomputed reciprocal (no div chain).
__global__ __launch_bounds__(256, 2) void gemm_bt(const unsigned short* __restrict__ A,
                                                  int lda, long aZs,
                                                  const unsigned short* __restrict__ B,
                                                  int ldb, long bZs,
                                                  const float* __restrict__ bias,
                                                  const float* __restrict__ resid,
                                                  const float* __restrict__ lvec,
                                                  void* __restrict__ out,
                                                  long ldo, long oZs,
                                                  int K, int mode, float scale) {
    __shared__ unsigned short As[128][72], Bs[128][72];  // 64-wide K-slab, pad 72
    int z = blockIdx.z;
    A += (size_t)z * aZs;
    B += (size_t)z * bZs;
    unsigned short* outu = (unsigned short*)out + (size_t)z * oZs;
    int m0 = blockIdx.y * 128, n0 = blockIdx.x * 128;
    int tid = threadIdx.x, w = tid >> 6, l = tid & 63;
    int lr = l & 15, lq = l >> 4, lk = lq * 8;
    int rbase = (w >> 1) * 64, cbase = (w & 1) * 64;
    f32x4 acc[4][4] = {};
    for (int k0 = 0; k0 < K; k0 += 64) {
        __syncthreads();
#pragma unroll
        for (int p = 0; p < 4; ++p) {
            int lin = p * 256 + tid;           // 1024 = 128 rows x 8 short8
            int r = lin >> 3, qq = lin & 7;
            *(short8*)&As[r][qq*8] = *(const short8*)(A + (size_t)(m0 + r)*lda + k0 + qq*8);
            *(short8*)&Bs[r][qq*8] = *(const short8*)(B + (size_t)(n0 + r)*ldb + k0 + qq*8);
        }
        __syncthreads();
        short8 af[4][2], bfv[4][2];
#pragma unroll
        for (int i = 0; i < 4; ++i)
#pragma unroll
            for (int ks = 0; ks < 2; ++ks) {
                af[i][ks]  = *(const short8*)&As[rbase + i*16 + lr][ks*32 + lk];
                bfv[i][ks] = *(const short8*)&Bs[cbase + i*16 + lr][ks*32 + lk];
            }
#pragma unroll
        for (int ks = 0; ks < 2; ++ks)
#pragma unroll
            for (int i = 0; i < 4; ++i)
#pragma unroll
                for (int j = 0; j < 4; ++j)
                    acc[i][j] = __builtin_amdgcn_mfma_f32_16x16x32_bf16(af[i][ks], bfv[j][ks], acc[i][j], 0, 0, 0);
    }
    int lq4 = lq * 4;
    if (mode == 2) {
        // reciprocal denominators: one load per output column group, hoisted
        float rlv[4];
#pragma unroll
        for (int j = 0; j < 4; ++j) rlv[j] = lvec[n0 + cbase + j*16 + lr];
        float* outf = (float*)out;
#pragma unroll
        for (int i = 0; i < 4; ++i) {
            int rowg = m0 + rbase + i*16 + lq4;
            float4 bq4 = *(const float4*)(bias + rowg);   // rowg % 4 == 0
            float bb[4] = {bq4.x, bq4.y, bq4.z, bq4.w};
            size_t ad[16];
            float lres[16];
#pragma unroll
            for (int j = 0; j < 4; ++j) {
                int colg = n0 + cbase + j*16 + lr;
                size_t base = ((size_t)(colg >> 12)) * 2097152 + (size_t)(colg & 4095);
#pragma unroll
                for (int r = 0; r < 4; ++r) {
                    ad[j*4+r] = base + (size_t)(rowg + r) * 4096;
                    lres[j*4+r] = resid[ad[j*4+r]];
                }
            }
#pragma unroll
            for (int j = 0; j < 4; ++j)
#pragma unroll
                for (int r = 0; r < 4; ++r)
                    outf[ad[j*4+r]] = acc[i][j][r] * rlv[j] + bb[r] + lres[j*4+r];
        }
        return;
    }
#pragma unroll
    for (int i = 0; i < 4; ++i) {
        int rowg = m0 + rbase + i*16 + lq4;
#pragma unroll
        for (int j = 0; j < 4; ++j) {
            int colg = n0 + cbase + j*16 + lr;
#pragma unroll
            for (int r = 0; r < 4; ++r) {
                float v = acc[i][j][r];
                int rr = rowg + r;
                if (mode == 0) {
                    outu[(size_t)rr * ldo + colg] = f2bf((v + bias[colg]) * scale);
                } else {
                    outu[(size_t)rr * ldo + colg] = f2bf(v + bias[rr]);
                }
            }
        }
    }
}

// =====================================================================
// 8-phase-style 256x256 MFMA core (T1+T2+T3+T4+T5), BK=64, 512 thr, 8 waves (2Mx4N)
// LDS 128 KiB: As/Bs [2][256][64] linear, both-sides XOR swizzle (verified 0-conflict
// in R2/R3 PV): source col pre-permuted ((l&7)^(l>>3))*8; read addr ^ (lr&7)<<4.
// Staging ledger (2 buffers, hazard-audited):
//   phase 1 of tile t: read all B-frags + A m-pair0; issue A(t+1) -> buf^1.  [4 loads]
//   phase 2: read A m-pair1; issue B-half0(t+2) -> buf cur (B read in ph1).  [2 loads]
//   phase 3: read A m-pair2; issue B-half1(t+2).                             [2 loads]
//   phase 4: read A m-pair3; vmcnt(4): drains B(t+1)+A(t+1), leaves B(t+2)
//     in flight. NEVER vmcnt(0) in steady state (T4).
// Each phase: lgkmcnt(0)+sched_barrier (rule #18), s_barrier, setprio(1),
// 16 MFMA, setprio(0), s_barrier.
// Output layout (verified): acc[mi][nj][r] = C[row][col] with
//   row (FIRST operand) = wr*128 + mi*16 + lq*4 + r, col (SECOND) = wc*64 + nj*16 + lr.
// =====================================================================
__device__ __forceinline__ void mm8_core(const unsigned short* __restrict__ A, int lda,
                                         const unsigned short* __restrict__ B, int ldb,
                                         int T,
                                         unsigned short (*As)[256][64],
                                         unsigned short (*Bs)[256][64],
                                         f32x4 acc[8][4]) {
    int tid = threadIdx.x, w = tid >> 6, l = tid & 63;
    int wr = w >> 2, wc = w & 3;
    int lr = l & 15, lq = l >> 4;
    int rsub = l >> 3, colp = ((l & 7) ^ rsub) << 3;   // pre-permuted source col
    int sw = (lr & 7) << 4;                             // read-side XOR
    int aw = w * 8;                                     // wave row offset in 64-row span

#define SG_A(buf, t_) { \
    const unsigned short* ap = A + (size_t)(t_) * 64; \
    __builtin_amdgcn_global_load_lds(GLO(ap + (size_t)(aw + rsub) * lda + colp),        LDSP(&As[buf][aw][0]), 16, 0, 0); \
    __builtin_amdgcn_global_load_lds(GLO(ap + (size_t)(64 + aw + rsub) * lda + colp),   LDSP(&As[buf][64 + aw][0]), 16, 0, 0); \
    __builtin_amdgcn_global_load_lds(GLO(ap + (size_t)(128 + aw + rsub) * lda + colp),  LDSP(&As[buf][128 + aw][0]), 16, 0, 0); \
    __builtin_amdgcn_global_load_lds(GLO(ap + (size_t)(192 + aw + rsub) * lda + colp),  LDSP(&As[buf][192 + aw][0]), 16, 0, 0); }
#define SG_B(buf, t_, h_) { \
    const unsigned short* bp = B + (size_t)(t_) * 64; int rb = (h_) * 128 + aw; \
    __builtin_amdgcn_global_load_lds(GLO(bp + (size_t)(rb + rsub) * ldb + colp),       LDSP(&Bs[buf][rb][0]), 16, 0, 0); \
    __builtin_amdgcn_global_load_lds(GLO(bp + (size_t)(rb + 64 + rsub) * ldb + colp),  LDSP(&Bs[buf][rb + 64][0]), 16, 0, 0); }
#define RD_B() { \
    const char* bsb = (const char*)Bs[cur]; \
    _Pragma("unroll") for (int nj = 0; nj < 4; ++nj) \
    _Pragma("unroll") for (int ks = 0; ks < 2; ++ks) { \
        int row = wc * 64 + nj * 16 + lr; \
        bf[nj][ks] = *(const short8*)(bsb + (((row << 7) + (ks << 6) + (lq << 4)) ^ sw)); } }
#define RD_A(p_) { \
    const char* asb = (const char*)As[cur]; \
    _Pragma("unroll") for (int i = 0; i < 2; ++i) \
    _Pragma("unroll") for (int ks = 0; ks < 2; ++ks) { \
        int row = wr * 128 + ((p_) * 2 + i) * 16 + lr; \
        af[i][ks] = *(const short8*)(asb + (((row << 7) + (ks << 6) + (lq << 4)) ^ sw)); } }
#define MM(p_) { \
    _Pragma("unroll") for (int ks = 0; ks < 2; ++ks) \
    _Pragma("unroll") for (int i = 0; i < 2; ++i) \
    _Pragma("unroll") for (int nj = 0; nj < 4; ++nj) \
        acc[(p_) * 2 + i][nj] = __builtin_amdgcn_mfma_f32_16x16x32_bf16(af[i][ks], bf[nj][ks], acc[(p_) * 2 + i][nj], 0, 0, 0); }
#define LGKM0 { asm volatile("s_waitcnt lgkmcnt(0)" ::: "memory"); __builtin_amdgcn_sched_barrier(0); }
#define VMC4 { asm volatile("s_waitcnt vmcnt(4)" ::: "memory"); __builtin_amdgcn_sched_barrier(0); }
#define VMC0 { asm volatile("s_waitcnt vmcnt(0)" ::: "memory"); __builtin_amdgcn_sched_barrier(0); }
#define BAR __builtin_amdgcn_s_barrier()

    // prologue: tile 0 (A+B) -> buf0; B(1) -> buf1; drain tile 0, keep B(1) in flight
    SG_A(0, 0); SG_B(0, 0, 0); SG_B(0, 0, 1);
    if (T > 1) { SG_B(1, 1, 0); SG_B(1, 1, 1); VMC4; } else { VMC0; }
    BAR;
    for (int t = 0; t < T; ++t) {
        int cur = t & 1, nxt = cur ^ 1;
        short8 bf[4][2], af[2][2];
        // phase 1
        RD_B(); RD_A(0);
        if (t + 1 < T) SG_A(nxt, t + 1);
        LGKM0; BAR;
        __builtin_amdgcn_s_setprio(1); MM(0); __builtin_amdgcn_s_setprio(0);
        BAR;
        // phase 2
        RD_A(1);
        if (t + 2 < T) SG_B(cur, t + 2, 0);
        LGKM0; BAR;
        __builtin_amdgcn_s_setprio(1); MM(1); __builtin_amdgcn_s_setprio(0);
        BAR;
        // phase 3
        RD_A(2);
        if (t + 2 < T) SG_B(cur, t + 2, 1);
        LGKM0; BAR;
        __builtin_amdgcn_s_setprio(1); MM(2); __builtin_amdgcn_s_setprio(0);
        BAR;
        // phase 4
        RD_A(3);
        if (t + 2 < T) { VMC4; } else { VMC0; }
        LGKM0; BAR;
        __builtin_amdgcn_s_setprio(1); MM(3); __builtin_amdgcn_s_setprio(0);
        BAR;
    }
#undef SG_A
#undef SG_B
#undef RD_B
#undef RD_A
#undef MM
#undef LGKM0
#undef VMC4
#undef VMC0
#undef BAR
}

// ---------------- S pass (SWAPPED operands): S^[j][i] tiles = k q^T ----------------
// First operand = K-tile (j = key pos), second = Q-tile (i = query row) ->
// acc[mi][nj][r] = S[i][j] with j = m0+wr*128+mi*16+lq*4+r (LANE-CONSECUTIVE over r),
// i = n0+wc*64+nj*16+lr. P[i][j] = bf16(exp(S)) written as packed ushort4 (8B/lane).
// Row-sum: per-lane sum over its 32 j-values, shfl_xor(16|32) across lq, 1 atomic/16 lanes.
// Handles up to 4 batches per launch: z<2 -> P0+z*16M, else P1+(z-2)*16M (pv8 convention).
__global__ __launch_bounds__(512, 2) void s8(const unsigned short* __restrict__ q,
                                             const unsigned short* __restrict__ k,
                                             float* __restrict__ lout,
                                             unsigned short* __restrict__ P0,
                                             unsigned short* __restrict__ P1,
                                             int nwg) {
    __shared__ unsigned short As[2][256][64], Bs[2][256][64];  // 128 KiB
    int wk = (int)(blockIdx.x & 7) * (nwg >> 3) + (int)(blockIdx.x >> 3);
    int z = wk >> 8, rem = wk & 255;
    int m0 = (rem >> 4) << 8, n0 = (rem & 15) << 8;   // m0 = j-tile, n0 = i-tile
    const unsigned short* A = k + (size_t)z * 2097152 + (size_t)m0 * 512;  // K first!
    const unsigned short* B = q + (size_t)z * 2097152 + (size_t)n0 * 512;
    f32x4 acc[8][4] = {};
    mm8_core(A, 512, B, 512, 8, As, Bs, acc);
    unsigned short* Pz = (z < 2) ? P0 + (size_t)z * 16777216
                                 : P1 + (size_t)(z - 2) * 16777216;
    float* lz = lout + z * 4096;
    int tid = threadIdx.x, w = tid >> 6, l = tid & 63;
    int wr = w >> 2, wc = w & 3, lr = l & 15, lq = l >> 4, lq4 = lq * 4;
    int jb = m0 + wr * 128;            // wave's j-strip base
    int ib = n0 + wc * 64;
#pragma unroll
    for (int nj = 0; nj < 4; ++nj) {
        int i = ib + nj * 16 + lr;
        unsigned short* prow = Pz + (size_t)i * 4096 + jb + lq4;
        float rs = 0.f;
#pragma unroll
        for (int mi = 0; mi < 8; ++mi) {
            float e0 = __expf(acc[mi][nj][0]);
            float e1 = __expf(acc[mi][nj][1]);
            float e2 = __expf(acc[mi][nj][2]);
            float e3 = __expf(acc[mi][nj][3]);
            rs += (e0 + e1) + (e2 + e3);
            ushort4 pk = make_ushort4(f2bf(e0), f2bf(e1), f2bf(e2), f2bf(e3));
            *(ushort4*)(prow + mi * 16) = pk;
        }
        rs += __shfl_xor(rs, 16);
        rs += __shfl_xor(rs, 32);
        if (lq == 0) atomicAdd(&lz[i], rs);
    }
}

// ---------------- PV pass: split-K=2, 256x256 tiles -> bf16 partials ----------------
// partial[s][z][m][n] = sum_{k in half s} P[z][m][k] * vt[n][(zofs+z)*4096 + k]
// P batches 0,1 at P0 (+z*16M), batches 2,3 at P1. Partials into dead qb/kb regions.
__global__ __launch_bounds__(512, 2) void pv8(const unsigned short* __restrict__ P0,
                                              const unsigned short* __restrict__ P1,
                                              const unsigned short* __restrict__ vt,
                                              unsigned short* __restrict__ part0,
                                              unsigned short* __restrict__ part1,
                                              int zofs, int nwg) {
    __shared__ unsigned short As[2][256][64], Bs[2][256][64];  // 128 KiB
    int wk = (int)(blockIdx.x & 7) * (nwg >> 3) + (int)(blockIdx.x >> 3);
    int half = nwg >> 1;
    int s = (wk >= half) ? 1 : 0;
    int rem = wk - s * half;
    int z = rem >> 5, t2 = rem & 31;                    // 32 tiles/batch: 16 m x 2 n
    int m0 = (t2 >> 1) << 8, n0 = (t2 & 1) << 8;
    const unsigned short* Pz = (z < 2) ? P0 + (size_t)z * 16777216
                                       : P1 + (size_t)(z - 2) * 16777216;
    const unsigned short* A = Pz + (size_t)m0 * 4096 + (size_t)s * 2048;
    const unsigned short* B = vt + (size_t)n0 * 32768 + (size_t)(zofs + z) * 4096 + (size_t)s * 2048;
    f32x4 acc[8][4] = {};
    mm8_core(A, 4096, B, 32768, 32, As, Bs, acc);
    unsigned short* pp = (s ? part1 : part0) + (size_t)z * 2097152 + (size_t)m0 * 512 + n0;
    int tid = threadIdx.x, w = tid >> 6, l = tid & 63;
    int wr = w >> 2, wc = w & 3, lr = l & 15, lq4 = (l >> 4) * 4;
#pragma unroll
    for (int mi = 0; mi < 8; ++mi)
#pragma unroll
        for (int nj = 0; nj < 4; ++nj)
#pragma unroll
            for (int r = 0; r < 4; ++r)
                pp[(size_t)(wr * 128 + mi * 16 + lq4 + r) * 512 + wc * 64 + nj * 16 + lr] = f2bf(acc[mi][nj][r]);
}

// ---------------- combine split-K partials: o = bf16(p0 + p1) ----------------
__global__ __launch_bounds__(256) void addcvt(const unsigned short* __restrict__ p0,
                                              const unsigned short* __restrict__ p1,
                                              unsigned short* __restrict__ o) {
    size_t i = ((size_t)blockIdx.x * 256 + threadIdx.x) * 8;
    short8 a = *(const short8*)(p0 + i), b = *(const short8*)(p1 + i);
    short8 r;
#pragma unroll
    for (int j = 0; j < 8; ++j)
        r[j] = (short)f2bf(bf2f((unsigned short)a[j]) + bf2f((unsigned short)b[j]));
    *(short8*)(o + i) = r;
}

extern "C" void kernel_launch(void* const* d_in, const int* in_sizes, int n_in,
                              void* d_out, int out_size, void* d_ws, size_t ws_size,
                              hipStream_t stream) {
    const float* x     = (const float*)d_in[0];
    const float* gamma = (const float*)d_in[1];
    const float* beta  = (const float*)d_in[2];
    const float* wq = (const float*)d_in[3];  const float* bq = (const float*)d_in[4];
    const float* wk = (const float*)d_in[5];  const float* bk = (const float*)d_in[6];
    const float* wv = (const float*)d_in[7];  const float* bv = (const float*)d_in[8];
    const float* wo = (const float*)d_in[9];  const float* bo = (const float*)d_in[10];

    // ---- base workspace layout (proven, ends at 136,448,000 B) ----
    char* wsp = (char*)d_ws;
    float* stats        = (float*)wsp;                    //   2 KB
    unsigned short* wqb = (unsigned short*)(wsp + 2048);  // 512 KB each
    unsigned short* wkb = wqb + 262144;
    unsigned short* wvb = wkb + 262144;
    unsigned short* wob = wvb + 262144;
    unsigned short* h   = wob + 262144;                   // 32 MB [B*HW, C] bf16
    unsigned short* qb  = h  + 16777216;                  // 32 MB
    unsigned short* kb  = qb + 16777216;                  // 32 MB
    unsigned short* vtb = kb + 16777216;                  // 32 MB [C, B*HW] bf16
    float* lbuf         = (float*)(vtb + 16777216);       // 128 KB softmax denoms
    unsigned short* Pw  = (unsigned short*)(lbuf + 32768);// mid path: +64 MB, ends 203.6 MB
    unsigned short* Pd  = (unsigned short*)d_out;         // 64 MB: 2 batches of P
    unsigned short* ob  = h;                              // alias: h dead after vT GEMM

    // mid path needs 203,556,864 B total
    const bool mid = ws_size >= 204000000ull;

    gn_stats<<<256, 256, 0, stream>>>(x, stats);
    wcvt<<<256, 256, 0, stream>>>(wq, wqb);
    wcvt<<<256, 256, 0, stream>>>(wk, wkb);
    wcvt<<<256, 256, 0, stream>>>(wv, wvb);
    wcvt<<<256, 256, 0, stream>>>(wo, wob);
    gn_apply<<<dim3(64, 8, 8), 256, 0, stream>>>(x, stats, gamma, beta, h);
    zero_l<<<32, 256, 0, stream>>>(lbuf);

    // q = alpha*(h wq^T + bq), k = h wk^T + bk  : [32768 x 512]
    gemm_bt<<<dim3(4, 256), 256, 0, stream>>>(h, 512, 0, wqb, 512, 0, bq, nullptr, nullptr,
                                              qb, 512, 0, 512, 0, ALPHA);
    gemm_bt<<<dim3(4, 256), 256, 0, stream>>>(h, 512, 0, wkb, 512, 0, bk, nullptr, nullptr,
                                              kb, 512, 0, 512, 0, 1.0f);
    // vT[c, pos] = wv h^T + bv : [512 x 32768]
    gemm_bt<<<dim3(256, 4), 256, 0, stream>>>(wvb, 512, 0, h, 512, 0, bv, nullptr, nullptr,
                                              vtb, 32768, 0, 512, 1, 1.0f);

    const long QS = (long)4096 * 512;   // per-batch q/k/o stride (elements)
    if (mid) {
        // ---- 2 chunks x 4 batches: P in d_out (2) + ws tail (2) ----
        // One s8 launch covers 4 batches (z<2 -> Pd, else Pw).
        // After each chunk's S-pass, that chunk's qb/kb regions are dead ->
        // reuse as split-K partial buffers (16 MB each), then addcvt -> ob.
        for (int c = 0; c < 2; ++c) {
            size_t z0 = (size_t)c * 4;
            s8<<<1024, 512, 0, stream>>>(qb + z0 * QS, kb + z0 * QS,
                                         lbuf + z0 * 4096, Pd, Pw, 1024);
            pv8<<<256, 512, 0, stream>>>(Pd, Pw, vtb,
                                         qb + z0 * QS, kb + z0 * QS, (int)z0, 256);
            addcvt<<<4096, 256, 0, stream>>>(qb + z0 * QS, kb + z0 * QS, ob + z0 * QS);
        }
    } else {
        // ---- 4 chunks x 2 batches: P in d_out only ----
        for (int c = 0; c < 4; ++c) {
            size_t z0 = (size_t)c * 2;
            s8<<<512, 512, 0, stream>>>(qb + z0 * QS, kb + z0 * QS,
                                        lbuf + z0 * 4096, Pd, Pd, 512);
            pv8<<<128, 512, 0, stream>>>(Pd, Pd, vtb,
                                         qb + z0 * QS, kb + z0 * QS, (int)z0, 128);
            addcvt<<<2048, 256, 0, stream>>>(qb + z0 * QS, kb + z0 * QS, ob + z0 * QS);
        }
    }
    // l -> 1/l (all 8 batches accumulated), then
    // out[b,c,hw] = (wo o_unnorm^T) * (1/l) + bo + x   (overwrites all of d_out)
    recip<<<32, 256, 0, stream>>>(lbuf);
    gemm_bt<<<dim3(256, 4), 256, 0, stream>>>(wob, 512, 0, ob, 512, 0, bo, x, lbuf,
                                              d_out, 0, 0, 512, 2, 1.0f);
}

// Round 8
// 681.499 us; speedup vs baseline: 1.3211x; 1.0632x over previous
//
#include <hip/hip_runtime.h>
#include <hip/hip_bf16.h>

// B=8, C=512, G=32, HW=4096. All matrix dims are multiples of 128 -> no guards.
typedef __attribute__((ext_vector_type(8))) short short8;
typedef __attribute__((ext_vector_type(4))) float f32x4;

#define ALPHA 0.044194173824159216f

// global_load_lds helpers: LDS dest is wave-uniform base + lane*16 (linear).
#define GLO(p) (const __attribute__((address_space(1))) void*)(p)
#define LDSP(p) (__attribute__((address_space(3))) void*)(p)

__device__ __forceinline__ unsigned short f2bf(float f) {
    union { float f; unsigned int u; } c; c.f = f;
    unsigned int u = c.u;
    return (unsigned short)((u + 0x7FFFu + ((u >> 16) & 1u)) >> 16);
}

__device__ __forceinline__ float bf2f(unsigned short s) {
    union { unsigned int u; float f; } c; c.u = ((unsigned int)s) << 16;
    return c.f;
}

// ---------------- GroupNorm stats: one block per (b,g), 16ch x 4096 contiguous ----
__global__ __launch_bounds__(256) void gn_stats(const float* __restrict__ x,
                                                float* __restrict__ stats) {
    int blk = blockIdx.x;  // b*32 + g
    const float4* src = (const float4*)(x + (size_t)blk * 65536);
    float s = 0.f, sq = 0.f;
    for (int i = threadIdx.x; i < 16384; i += 256) {
        float4 v = src[i];
        s  += v.x + v.y + v.z + v.w;
        sq += v.x*v.x + v.y*v.y + v.z*v.z + v.w*v.w;
    }
    for (int off = 32; off; off >>= 1) {
        s  += __shfl_down(s, off);
        sq += __shfl_down(sq, off);
    }
    __shared__ float ss[4], ssq[4];
    int wid = threadIdx.x >> 6;
    if ((threadIdx.x & 63) == 0) { ss[wid] = s; ssq[wid] = sq; }
    __syncthreads();
    if (threadIdx.x == 0) {
        float S = ss[0]+ss[1]+ss[2]+ss[3], Q = ssq[0]+ssq[1]+ssq[2]+ssq[3];
        float mu = S * (1.f/65536.f);
        float var = Q * (1.f/65536.f) - mu*mu;
        stats[blk] = mu;
        stats[256 + blk] = rsqrtf(var + 1e-6f);
    }
}

// ---------------- weight fp32 -> bf16 ----------------
__global__ __launch_bounds__(256) void wcvt(const float* __restrict__ s,
                                            unsigned short* __restrict__ d) {
    int i = blockIdx.x * 1024 + threadIdx.x * 4;
    float4 v = *(const float4*)(s + i);
    ushort4 o = make_ushort4(f2bf(v.x), f2bf(v.y), f2bf(v.z), f2bf(v.w));
    *(ushort4*)(d + i) = o;
}

// ---------------- zero the softmax-denominator accumulator ----------------
__global__ __launch_bounds__(256) void zero_l(float* __restrict__ l) {
    ((float4*)l)[blockIdx.x * 256 + threadIdx.x] = make_float4(0.f, 0.f, 0.f, 0.f);
}

// ---------------- invert softmax denominators in place: l -> 1/l ----------------
__global__ __launch_bounds__(256) void recip(float* __restrict__ l) {
    int i = blockIdx.x * 256 + threadIdx.x;
    float4 v = ((const float4*)l)[i];
    ((float4*)l)[i] = make_float4(1.f / v.x, 1.f / v.y, 1.f / v.z, 1.f / v.w);
}

// ------- GN apply + transpose: x[b][c][hw] fp32 -> h[(b*4096+hw)][c] bf16 -------
__global__ __launch_bounds__(256) void gn_apply(const float* __restrict__ x,
                                                const float* __restrict__ stats,
                                                const float* __restrict__ gamma,
                                                const float* __restrict__ beta,
                                                unsigned short* __restrict__ h) {
    __shared__ unsigned short t[64][72];  // [hw_local][c_local], pad 72
    int b = blockIdx.z, c0 = blockIdx.y * 64, hw0 = blockIdx.x * 64;
    int tid = threadIdx.x;
#pragma unroll
    for (int rep = 0; rep < 4; ++rep) {
        int lin = rep * 256 + tid;         // 1024 = 64 c-rows x 16 float4
        int row = lin >> 4;                // c_local
        int c4  = lin & 15;                // float4 idx along hw
        int c   = c0 + row;
        const float4* src = (const float4*)(x + ((size_t)(b*512 + c) << 12) + hw0);
        float4 v = src[c4];
        int sidx = b*32 + (c >> 4);
        float mu = stats[sidx], rs = stats[256 + sidx];
        float ga = gamma[c] * rs, be = beta[c] - mu * ga;
        t[c4*4+0][row] = f2bf(v.x * ga + be);
        t[c4*4+1][row] = f2bf(v.y * ga + be);
        t[c4*4+2][row] = f2bf(v.z * ga + be);
        t[c4*4+3][row] = f2bf(v.w * ga + be);
    }
    __syncthreads();
#pragma unroll
    for (int rep = 0; rep < 2; ++rep) {
        int lin = rep * 256 + tid;         // 512 = 64 hw-rows x 8 groups
        int row = lin >> 3;                // hw_local
        int u8  = lin & 7;
        unsigned short* dst = h + (((size_t)(b*4096 + hw0 + row)) << 9) + c0 + u8*8;
        *(short8*)dst = *(const short8*)&t[row][u8*8];
    }
}

// ---------------- universal 128x128 bf16 MFMA GEMM, BK=64 (reg-staged, proven) ----
// C[m,n] = sum_k A[m,k] * B[n,k]
// mode 0: out bf16, out[m*ldo+n] = bf16((acc + bias[n]) * scale)          (unused now)
// mode 1: out bf16, out[m*ldo+n] = bf16(acc + bias[m])                    (vT proj)
// mode 2: out fp32 d_out[b][m][hw], n = b*4096+hw:
//           acc * rlvec[n] + bias[m] + resid   (rlvec holds 1/l)          (o-proj)
__global__ __launch_bounds__(256, 2) void gemm_bt(const unsigned short* __restrict__ A,
                                                  int lda, long aZs,
                                                  const unsigned short* __restrict__ B,
                                                  int ldb, long bZs,
                                                  const float* __restrict__ bias,
                                                  const float* __restrict__ resid,
                                                  const float* __restrict__ lvec,
                                                  void* __restrict__ out,
                                                  long ldo, long oZs,
                                                  int K, int mode, float scale) {
    __shared__ unsigned short As[128][72], Bs[128][72];  // 64-wide K-slab, pad 72
    int z = blockIdx.z;
    A += (size_t)z * aZs;
    B += (size_t)z * bZs;
    unsigned short* outu = (unsigned short*)out + (size_t)z * oZs;
    int m0 = blockIdx.y * 128, n0 = blockIdx.x * 128;
    int tid = threadIdx.x, w = tid >> 6, l = tid & 63;
    int lr = l & 15, lq = l >> 4, lk = lq * 8;
    int rbase = (w >> 1) * 64, cbase = (w & 1) * 64;
    f32x4 acc[4][4] = {};
    for (int k0 = 0; k0 < K; k0 += 64) {
        __syncthreads();
#pragma unroll
        for (int p = 0; p < 4; ++p) {
            int lin = p * 256 + tid;           // 1024 = 128 rows x 8 short8
            int r = lin >> 3, qq = lin & 7;
            *(short8*)&As[r][qq*8] = *(const short8*)(A + (size_t)(m0 + r)*lda + k0 + qq*8);
            *(short8*)&Bs[r][qq*8] = *(const short8*)(B + (size_t)(n0 + r)*ldb + k0 + qq*8);
        }
        __syncthreads();
        short8 af[4][2], bfv[4][2];
#pragma unroll
        for (int i = 0; i < 4; ++i)
#pragma unroll
            for (int ks = 0; ks < 2; ++ks) {
                af[i][ks]  = *(const short8*)&As[rbase + i*16 + lr][ks*32 + lk];
                bfv[i][ks] = *(const short8*)&Bs[cbase + i*16 + lr][ks*32 + lk];
            }
#pragma unroll
        for (int ks = 0; ks < 2; ++ks)
#pragma unroll
            for (int i = 0; i < 4; ++i)
#pragma unroll
                for (int j = 0; j < 4; ++j)
                    acc[i][j] = __builtin_amdgcn_mfma_f32_16x16x32_bf16(af[i][ks], bfv[j][ks], acc[i][j], 0, 0, 0);
    }
    int lq4 = lq * 4;
    if (mode == 2) {
        // reciprocal denominators: one load per output column group, hoisted
        float rlv[4];
#pragma unroll
        for (int j = 0; j < 4; ++j) rlv[j] = lvec[n0 + cbase + j*16 + lr];
        float* outf = (float*)out;
#pragma unroll
        for (int i = 0; i < 4; ++i) {
            int rowg = m0 + rbase + i*16 + lq4;
            float4 bq4 = *(const float4*)(bias + rowg);   // rowg % 4 == 0
            float bb[4] = {bq4.x, bq4.y, bq4.z, bq4.w};
            size_t ad[16];
            float lres[16];
#pragma unroll
            for (int j = 0; j < 4; ++j) {
                int colg = n0 + cbase + j*16 + lr;
                size_t base = ((size_t)(colg >> 12)) * 2097152 + (size_t)(colg & 4095);
#pragma unroll
                for (int r = 0; r < 4; ++r) {
                    ad[j*4+r] = base + (size_t)(rowg + r) * 4096;
                    lres[j*4+r] = resid[ad[j*4+r]];
                }
            }
#pragma unroll
            for (int j = 0; j < 4; ++j)
#pragma unroll
                for (int r = 0; r < 4; ++r)
                    outf[ad[j*4+r]] = acc[i][j][r] * rlv[j] + bb[r] + lres[j*4+r];
        }
        return;
    }
#pragma unroll
    for (int i = 0; i < 4; ++i) {
        int rowg = m0 + rbase + i*16 + lq4;
#pragma unroll
        for (int j = 0; j < 4; ++j) {
            int colg = n0 + cbase + j*16 + lr;
#pragma unroll
            for (int r = 0; r < 4; ++r) {
                float v = acc[i][j][r];
                int rr = rowg + r;
                if (mode == 0) {
                    outu[(size_t)rr * ldo + colg] = f2bf((v + bias[colg]) * scale);
                } else {
                    outu[(size_t)rr * ldo + colg] = f2bf(v + bias[rr]);
                }
            }
        }
    }
}

// ---------------- merged q+k projection: stage h-tile ONCE, two weight tiles ----
// q[m,n] = alpha*(h[m,:] wq[n,:] + bq[n]); k[m,n] = h[m,:] wk[n,:] + bk[n]
// 3 LDS tiles (55 KB) -> still 2 blocks/CU. Halves the h re-fetch vs 2 launches.
__global__ __launch_bounds__(256, 2) void qk2(const unsigned short* __restrict__ A,
                                              const unsigned short* __restrict__ Wq,
                                              const unsigned short* __restrict__ Wk,
                                              const float* __restrict__ biasq,
                                              const float* __restrict__ biask,
                                              unsigned short* __restrict__ qo,
                                              unsigned short* __restrict__ ko) {
    __shared__ unsigned short As[128][72], Bq[128][72], Bk[128][72];
    int m0 = blockIdx.y * 128, n0 = blockIdx.x * 128;
    int tid = threadIdx.x, w = tid >> 6, l = tid & 63;
    int lr = l & 15, lq = l >> 4, lk = lq * 8;
    int rbase = (w >> 1) * 64, cbase = (w & 1) * 64;
    f32x4 aq[4][4] = {}, ak[4][4] = {};
    for (int k0 = 0; k0 < 512; k0 += 64) {
        __syncthreads();
#pragma unroll
        for (int p = 0; p < 4; ++p) {
            int lin = p * 256 + tid;           // 1024 = 128 rows x 8 short8
            int r = lin >> 3, qq = lin & 7;
            *(short8*)&As[r][qq*8] = *(const short8*)(A  + (size_t)(m0 + r)*512 + k0 + qq*8);
            *(short8*)&Bq[r][qq*8] = *(const short8*)(Wq + (size_t)(n0 + r)*512 + k0 + qq*8);
            *(short8*)&Bk[r][qq*8] = *(const short8*)(Wk + (size_t)(n0 + r)*512 + k0 + qq*8);
        }
        __syncthreads();
#pragma unroll
        for (int ks = 0; ks < 2; ++ks) {
            short8 af[4], bfq[4], bfk[4];
#pragma unroll
            for (int i = 0; i < 4; ++i) {
                af[i]  = *(const short8*)&As[rbase + i*16 + lr][ks*32 + lk];
                bfq[i] = *(const short8*)&Bq[cbase + i*16 + lr][ks*32 + lk];
                bfk[i] = *(const short8*)&Bk[cbase + i*16 + lr][ks*32 + lk];
            }
#pragma unroll
            for (int i = 0; i < 4; ++i)
#pragma unroll
                for (int j = 0; j < 4; ++j) {
                    aq[i][j] = __builtin_amdgcn_mfma_f32_16x16x32_bf16(af[i], bfq[j], aq[i][j], 0, 0, 0);
                    ak[i][j] = __builtin_amdgcn_mfma_f32_16x16x32_bf16(af[i], bfk[j], ak[i][j], 0, 0, 0);
                }
        }
    }
    int lq4 = lq * 4;
#pragma unroll
    for (int i = 0; i < 4; ++i) {
        int rowg = m0 + rbase + i*16 + lq4;
#pragma unroll
        for (int j = 0; j < 4; ++j) {
            int colg = n0 + cbase + j*16 + lr;
            float bqv = biasq[colg], bkv = biask[colg];
#pragma unroll
            for (int r = 0; r < 4; ++r) {
                qo[(size_t)(rowg + r) * 512 + colg] = f2bf((aq[i][j][r] + bqv) * ALPHA);
                ko[(size_t)(rowg + r) * 512 + colg] = f2bf(ak[i][j][r] + bkv);
            }
        }
    }
}

// =====================================================================
// 8-phase-style 256x256 MFMA core (T1+T2+T3+T4+T5), BK=64, 512 thr, 8 waves (2Mx4N)
// LDS 128 KiB: As/Bs [2][256][64] linear, both-sides XOR swizzle (verified 0-conflict):
// source col pre-permuted ((l&7)^(l>>3))*8; read addr ^ (lr&7)<<4.
// m201-faithful phase order: {reads; stage; BAR; lgkmcnt(0); setprio(1); 16 MFMA;
// setprio(0); BAR} — lgkm wait AFTER the barrier so barrier-sync time absorbs
// ds_read latency. vmcnt(4) at ph4 BEFORE the barrier (own loads drained, barrier
// publishes globally). NEVER vmcnt(0) in steady state (T4).
// Ledger (steady state, entering tile t: B(t+1)=4 outstanding):
//   ph1 reads B-all + A-q0; +SG_A(t+1) -> 8 outstanding
//   ph2 reads A-q1; +SG_B0(t+2) -> 10
//   ph3 reads A-q2; +SG_B1(t+2) -> 12
//   ph4 reads A-q3; vmcnt(4) drains B(t+1)+A(t+1), leaves B(t+2)=4.
// Buffer WAR audited: SG_A(t+1)->buf^1 A-region last read t-1 ph4 (2 BARs ago);
// SG_B(t+2)->buf cur B-region fully read ph1 (1 BAR ago).
// Output layout (verified): acc[mi][nj][r] = C[row][col],
//   row (FIRST operand) = wr*128 + mi*16 + lq*4 + r, col (SECOND) = wc*64 + nj*16 + lr.
// =====================================================================
__device__ __forceinline__ void mm8_core(const unsigned short* __restrict__ A, int lda,
                                         const unsigned short* __restrict__ B, int ldb,
                                         int T,
                                         unsigned short (*As)[256][64],
                                         unsigned short (*Bs)[256][64],
                                         f32x4 acc[8][4]) {
    int tid = threadIdx.x, w = tid >> 6, l = tid & 63;
    int wr = w >> 2, wc = w & 3;
    int lr = l & 15, lq = l >> 4;
    int rsub = l >> 3, colp = ((l & 7) ^ rsub) << 3;   // pre-permuted source col
    int sw = (lr & 7) << 4;                             // read-side XOR
    int aw = w * 8;                                     // wave row offset in 64-row span

#define SG_A(buf, t_) { \
    const unsigned short* ap = A + (size_t)(t_) * 64; \
    __builtin_amdgcn_global_load_lds(GLO(ap + (size_t)(aw + rsub) * lda + colp),        LDSP(&As[buf][aw][0]), 16, 0, 0); \
    __builtin_amdgcn_global_load_lds(GLO(ap + (size_t)(64 + aw + rsub) * lda + colp),   LDSP(&As[buf][64 + aw][0]), 16, 0, 0); \
    __builtin_amdgcn_global_load_lds(GLO(ap + (size_t)(128 + aw + rsub) * lda + colp),  LDSP(&As[buf][128 + aw][0]), 16, 0, 0); \
    __builtin_amdgcn_global_load_lds(GLO(ap + (size_t)(192 + aw + rsub) * lda + colp),  LDSP(&As[buf][192 + aw][0]), 16, 0, 0); }
#define SG_B(buf, t_, h_) { \
    const unsigned short* bp = B + (size_t)(t_) * 64; int rb = (h_) * 128 + aw; \
    __builtin_amdgcn_global_load_lds(GLO(bp + (size_t)(rb + rsub) * ldb + colp),       LDSP(&Bs[buf][rb][0]), 16, 0, 0); \
    __builtin_amdgcn_global_load_lds(GLO(bp + (size_t)(rb + 64 + rsub) * ldb + colp),  LDSP(&Bs[buf][rb + 64][0]), 16, 0, 0); }
#define RD_B() { \
    const char* bsb = (const char*)Bs[cur]; \
    _Pragma("unroll") for (int nj = 0; nj < 4; ++nj) \
    _Pragma("unroll") for (int ks = 0; ks < 2; ++ks) { \
        int row = wc * 64 + nj * 16 + lr; \
        bf[nj][ks] = *(const short8*)(bsb + (((row << 7) + (ks << 6) + (lq << 4)) ^ sw)); } }
#define RD_A(p_) { \
    const char* asb = (const char*)As[cur]; \
    _Pragma("unroll") for (int i = 0; i < 2; ++i) \
    _Pragma("unroll") for (int ks = 0; ks < 2; ++ks) { \
        int row = wr * 128 + ((p_) * 2 + i) * 16 + lr; \
        af[i][ks] = *(const short8*)(asb + (((row << 7) + (ks << 6) + (lq << 4)) ^ sw)); } }
#define MM(p_) { \
    _Pragma("unroll") for (int ks = 0; ks < 2; ++ks) \
    _Pragma("unroll") for (int i = 0; i < 2; ++i) \
    _Pragma("unroll") for (int nj = 0; nj < 4; ++nj) \
        acc[(p_) * 2 + i][nj] = __builtin_amdgcn_mfma_f32_16x16x32_bf16(af[i][ks], bf[nj][ks], acc[(p_) * 2 + i][nj], 0, 0, 0); }
#define LGKM0 { asm volatile("s_waitcnt lgkmcnt(0)" ::: "memory"); __builtin_amdgcn_sched_barrier(0); }
#define VMC4 { asm volatile("s_waitcnt vmcnt(4)" ::: "memory"); __builtin_amdgcn_sched_barrier(0); }
#define VMC0 { asm volatile("s_waitcnt vmcnt(0)" ::: "memory"); __builtin_amdgcn_sched_barrier(0); }
#define BAR __builtin_amdgcn_s_barrier()

    // prologue: tile 0 (A+B) -> buf0; B(1) -> buf1; drain tile 0, keep B(1) in flight
    SG_A(0, 0); SG_B(0, 0, 0); SG_B(0, 0, 1);
    if (T > 1) { SG_B(1, 1, 0); SG_B(1, 1, 1); VMC4; } else { VMC0; }
    BAR;
    for (int t = 0; t < T; ++t) {
        int cur = t & 1, nxt = cur ^ 1;
        short8 bf[4][2], af[2][2];
        // phase 1
        RD_B(); RD_A(0);
        if (t + 1 < T) SG_A(nxt, t + 1);
        BAR; LGKM0;
        __builtin_amdgcn_s_setprio(1); MM(0); __builtin_amdgcn_s_setprio(0);
        BAR;
        // phase 2
        RD_A(1);
        if (t + 2 < T) SG_B(cur, t + 2, 0);
        BAR; LGKM0;
        __builtin_amdgcn_s_setprio(1); MM(1); __builtin_amdgcn_s_setprio(0);
        BAR;
        // phase 3
        RD_A(2);
        if (t + 2 < T) SG_B(cur, t + 2, 1);
        BAR; LGKM0;
        __builtin_amdgcn_s_setprio(1); MM(2); __builtin_amdgcn_s_setprio(0);
        BAR;
        // phase 4
        RD_A(3);
        if (t + 2 < T) { VMC4; } else { VMC0; }
        BAR; LGKM0;
        __builtin_amdgcn_s_setprio(1); MM(3); __builtin_amdgcn_s_setprio(0);
        BAR;
    }
#undef SG_A
#undef SG_B
#undef RD_B
#undef RD_A
#undef MM
#undef LGKM0
#undef VMC4
#undef VMC0
#undef BAR
}

// ---------------- S pass (SWAPPED operands): S^[j][i] tiles = k q^T ----------------
// First operand = K-tile (j = key pos), second = Q-tile (i = query row) ->
// acc[mi][nj][r] = S[i][j] with j = m0+wr*128+mi*16+lq*4+r (LANE-CONSECUTIVE over r),
// i = n0+wc*64+nj*16+lr. P[i][j] = bf16(exp(S)) written as packed ushort4 (8B/lane).
// Row-sum: per-lane sum over its 32 j-values, shfl_xor(16|32) across lq, 1 atomic/16 lanes.
// Handles up to 4 batches per launch: z<2 -> P0+z*16M, else P1+(z-2)*16M (pv8 convention).
__global__ __launch_bounds__(512, 2) void s8(const unsigned short* __restrict__ q,
                                             const unsigned short* __restrict__ k,
                                             float* __restrict__ lout,
                                             unsigned short* __restrict__ P0,
                                             unsigned short* __restrict__ P1,
                                             int nwg) {
    __shared__ unsigned short As[2][256][64], Bs[2][256][64];  // 128 KiB
    int wk = (int)(blockIdx.x & 7) * (nwg >> 3) + (int)(blockIdx.x >> 3);
    int z = wk >> 8, rem = wk & 255;
    int m0 = (rem >> 4) << 8, n0 = (rem & 15) << 8;   // m0 = j-tile, n0 = i-tile
    const unsigned short* A = k + (size_t)z * 2097152 + (size_t)m0 * 512;  // K first!
    const unsigned short* B = q + (size_t)z * 2097152 + (size_t)n0 * 512;
    f32x4 acc[8][4] = {};
    mm8_core(A, 512, B, 512, 8, As, Bs, acc);
    unsigned short* Pz = (z < 2) ? P0 + (size_t)z * 16777216
                                 : P1 + (size_t)(z - 2) * 16777216;
    float* lz = lout + z * 4096;
    int tid = threadIdx.x, w = tid >> 6, l = tid & 63;
    int wr = w >> 2, wc = w & 3, lr = l & 15, lq = l >> 4, lq4 = lq * 4;
    int jb = m0 + wr * 128;            // wave's j-strip base
    int ib = n0 + wc * 64;
#pragma unroll
    for (int nj = 0; nj < 4; ++nj) {
        int i = ib + nj * 16 + lr;
        unsigned short* prow = Pz + (size_t)i * 4096 + jb + lq4;
        float rs = 0.f;
#pragma unroll
        for (int mi = 0; mi < 8; ++mi) {
            float e0 = __expf(acc[mi][nj][0]);
            float e1 = __expf(acc[mi][nj][1]);
            float e2 = __expf(acc[mi][nj][2]);
            float e3 = __expf(acc[mi][nj][3]);
            rs += (e0 + e1) + (e2 + e3);
            ushort4 pk = make_ushort4(f2bf(e0), f2bf(e1), f2bf(e2), f2bf(e3));
            *(ushort4*)(prow + mi * 16) = pk;
        }
        rs += __shfl_xor(rs, 16);
        rs += __shfl_xor(rs, 32);
        if (lq == 0) atomicAdd(&lz[i], rs);
    }
}

// ---------------- PV pass: split-K=2, 256x256 tiles -> bf16 partials ----------------
// partial[s][z][m][n] = sum_{k in half s} P[z][m][k] * vt[n][(zofs+z)*4096 + k]
// P batches 0,1 at P0 (+z*16M), batches 2,3 at P1. Partials into dead qb/kb regions.
__global__ __launch_bounds__(512, 2) void pv8(const unsigned short* __restrict__ P0,
                                              const unsigned short* __restrict__ P1,
                                              const unsigned short* __restrict__ vt,
                                              unsigned short* __restrict__ part0,
                                              unsigned short* __restrict__ part1,
                                              int zofs, int nwg) {
    __shared__ unsigned short As[2][256][64], Bs[2][256][64];  // 128 KiB
    int wk = (int)(blockIdx.x & 7) * (nwg >> 3) + (int)(blockIdx.x >> 3);
    int half = nwg >> 1;
    int s = (wk >= half) ? 1 : 0;
    int rem = wk - s * half;
    int z = rem >> 5, t2 = rem & 31;                    // 32 tiles/batch: 16 m x 2 n
    int m0 = (t2 >> 1) << 8, n0 = (t2 & 1) << 8;
    const unsigned short* Pz = (z < 2) ? P0 + (size_t)z * 16777216
                                       : P1 + (size_t)(z - 2) * 16777216;
    const unsigned short* A = Pz + (size_t)m0 * 4096 + (size_t)s * 2048;
    const unsigned short* B = vt + (size_t)n0 * 32768 + (size_t)(zofs + z) * 4096 + (size_t)s * 2048;
    f32x4 acc[8][4] = {};
    mm8_core(A, 4096, B, 32768, 32, As, Bs, acc);
    unsigned short* pp = (s ? part1 : part0) + (size_t)z * 2097152 + (size_t)m0 * 512 + n0;
    int tid = threadIdx.x, w = tid >> 6, l = tid & 63;
    int wr = w >> 2, wc = w & 3, lr = l & 15, lq4 = (l >> 4) * 4;
#pragma unroll
    for (int mi = 0; mi < 8; ++mi)
#pragma unroll
        for (int nj = 0; nj < 4; ++nj)
#pragma unroll
            for (int r = 0; r < 4; ++r)
                pp[(size_t)(wr * 128 + mi * 16 + lq4 + r) * 512 + wc * 64 + nj * 16 + lr] = f2bf(acc[mi][nj][r]);
}

// ---------------- combine split-K partials: o = bf16(p0 + p1) ----------------
__global__ __launch_bounds__(256) void addcvt(const unsigned short* __restrict__ p0,
                                              const unsigned short* __restrict__ p1,
                                              unsigned short* __restrict__ o) {
    size_t i = ((size_t)blockIdx.x * 256 + threadIdx.x) * 8;
    short8 a = *(const short8*)(p0 + i), b = *(const short8*)(p1 + i);
    short8 r;
#pragma unroll
    for (int j = 0; j < 8; ++j)
        r[j] = (short)f2bf(bf2f((unsigned short)a[j]) + bf2f((unsigned short)b[j]));
    *(short8*)(o + i) = r;
}

extern "C" void kernel_launch(void* const* d_in, const int* in_sizes, int n_in,
                              void* d_out, int out_size, void* d_ws, size_t ws_size,
                              hipStream_t stream) {
    const float* x     = (const float*)d_in[0];
    const float* gamma = (const float*)d_in[1];
    const float* beta  = (const float*)d_in[2];
    const float* wq = (const float*)d_in[3];  const float* bq = (const float*)d_in[4];
    const float* wk = (const float*)d_in[5];  const float* bk = (const float*)d_in[6];
    const float* wv = (const float*)d_in[7];  const float* bv = (const float*)d_in[8];
    const float* wo = (const float*)d_in[9];  const float* bo = (const float*)d_in[10];

    // ---- base workspace layout (proven, ends at 136,448,000 B) ----
    char* wsp = (char*)d_ws;
    float* stats        = (float*)wsp;                    //   2 KB
    unsigned short* wqb = (unsigned short*)(wsp + 2048);  // 512 KB each
    unsigned short* wkb = wqb + 262144;
    unsigned short* wvb = wkb + 262144;
    unsigned short* wob = wvb + 262144;
    unsigned short* h   = wob + 262144;                   // 32 MB [B*HW, C] bf16
    unsigned short* qb  = h  + 16777216;                  // 32 MB
    unsigned short* kb  = qb + 16777216;                  // 32 MB
    unsigned short* vtb = kb + 16777216;                  // 32 MB [C, B*HW] bf16
    float* lbuf         = (float*)(vtb + 16777216);       // 128 KB softmax denoms
    unsigned short* Pw  = (unsigned short*)(lbuf + 32768);// mid path: +64 MB, ends 203.6 MB
    unsigned short* Pd  = (unsigned short*)d_out;         // 64 MB: 2 batches of P
    unsigned short* ob  = h;                              // alias: h dead after vT GEMM

    // mid path needs 203,556,864 B total
    const bool mid = ws_size >= 204000000ull;

    gn_stats<<<256, 256, 0, stream>>>(x, stats);
    wcvt<<<256, 256, 0, stream>>>(wq, wqb);
    wcvt<<<256, 256, 0, stream>>>(wk, wkb);
    wcvt<<<256, 256, 0, stream>>>(wv, wvb);
    wcvt<<<256, 256, 0, stream>>>(wo, wob);
    gn_apply<<<dim3(64, 8, 8), 256, 0, stream>>>(x, stats, gamma, beta, h);
    zero_l<<<32, 256, 0, stream>>>(lbuf);

    // q = alpha*(h wq^T + bq), k = h wk^T + bk  : [32768 x 512] — ONE launch, h staged once
    qk2<<<dim3(4, 256), 256, 0, stream>>>(h, wqb, wkb, bq, bk, qb, kb);
    // vT[c, pos] = wv h^T + bv : [512 x 32768]
    gemm_bt<<<dim3(256, 4), 256, 0, stream>>>(wvb, 512, 0, h, 512, 0, bv, nullptr, nullptr,
                                              vtb, 32768, 0, 512, 1, 1.0f);

    const long QS = (long)4096 * 512;   // per-batch q/k/o stride (elements)
    if (mid) {
        // ---- 2 chunks x 4 batches: P in d_out (2) + ws tail (2) ----
        // One s8 launch covers 4 batches (z<2 -> Pd, else Pw).
        // After each chunk's S-pass, that chunk's qb/kb regions are dead ->
        // reuse as split-K partial buffers (16 MB each), then addcvt -> ob.
        for (int c = 0; c < 2; ++c) {
            size_t z0 = (size_t)c * 4;
            s8<<<1024, 512, 0, stream>>>(qb + z0 * QS, kb + z0 * QS,
                                         lbuf + z0 * 4096, Pd, Pw, 1024);
            pv8<<<256, 512, 0, stream>>>(Pd, Pw, vtb,
                                         qb + z0 * QS, kb + z0 * QS, (int)z0, 256);
            addcvt<<<4096, 256, 0, stream>>>(qb + z0 * QS, kb + z0 * QS, ob + z0 * QS);
        }
    } else {
        // ---- 4 chunks x 2 batches: P in d_out only ----
        for (int c = 0; c < 4; ++c) {
            size_t z0 = (size_t)c * 2;
            s8<<<512, 512, 0, stream>>>(qb + z0 * QS, kb + z0 * QS,
                                        lbuf + z0 * 4096, Pd, Pd, 512);
            pv8<<<128, 512, 0, stream>>>(Pd, Pd, vtb,
                                         qb + z0 * QS, kb + z0 * QS, (int)z0, 128);
            addcvt<<<2048, 256, 0, stream>>>(qb + z0 * QS, kb + z0 * QS, ob + z0 * QS);
        }
    }
    // l -> 1/l (all 8 batches accumulated), then
    // out[b,c,hw] = (wo o_unnorm^T) * (1/l) + bo + x   (overwrites all of d_out)
    recip<<<32, 256, 0, stream>>>(lbuf);
    gemm_bt<<<dim3(256, 4), 256, 0, stream>>>(wob, 512, 0, ob, 512, 0, bo, x, lbuf,
                                              d_out, 0, 0, 512, 2, 1.0f);
}

// Round 9
// 674.312 us; speedup vs baseline: 1.3352x; 1.0107x over previous
//
#include <hip/hip_runtime.h>
#include <hip/hip_bf16.h>

// B=8, C=512, G=32, HW=4096. All matrix dims are multiples of 128 -> no guards.
typedef __attribute__((ext_vector_type(8))) short short8;
typedef __attribute__((ext_vector_type(4))) float f32x4;

#define ALPHA 0.044194173824159216f

// global_load_lds helpers: LDS dest is wave-uniform base + lane*16 (linear).
#define GLO(p) (const __attribute__((address_space(1))) void*)(p)
#define LDSP(p) (__attribute__((address_space(3))) void*)(p)

__device__ __forceinline__ unsigned short f2bf(float f) {
    union { float f; unsigned int u; } c; c.f = f;
    unsigned int u = c.u;
    return (unsigned short)((u + 0x7FFFu + ((u >> 16) & 1u)) >> 16);
}

__device__ __forceinline__ float bf2f(unsigned short s) {
    union { unsigned int u; float f; } c; c.u = ((unsigned int)s) << 16;
    return c.f;
}

// ---------------- GroupNorm stats: one block per (b,g), 16ch x 4096 contiguous ----
__global__ __launch_bounds__(256) void gn_stats(const float* __restrict__ x,
                                                float* __restrict__ stats) {
    int blk = blockIdx.x;  // b*32 + g
    const float4* src = (const float4*)(x + (size_t)blk * 65536);
    float s = 0.f, sq = 0.f;
    for (int i = threadIdx.x; i < 16384; i += 256) {
        float4 v = src[i];
        s  += v.x + v.y + v.z + v.w;
        sq += v.x*v.x + v.y*v.y + v.z*v.z + v.w*v.w;
    }
    for (int off = 32; off; off >>= 1) {
        s  += __shfl_down(s, off);
        sq += __shfl_down(sq, off);
    }
    __shared__ float ss[4], ssq[4];
    int wid = threadIdx.x >> 6;
    if ((threadIdx.x & 63) == 0) { ss[wid] = s; ssq[wid] = sq; }
    __syncthreads();
    if (threadIdx.x == 0) {
        float S = ss[0]+ss[1]+ss[2]+ss[3], Q = ssq[0]+ssq[1]+ssq[2]+ssq[3];
        float mu = S * (1.f/65536.f);
        float var = Q * (1.f/65536.f) - mu*mu;
        stats[blk] = mu;
        stats[256 + blk] = rsqrtf(var + 1e-6f);
    }
}

// ---------------- weight fp32 -> bf16 ----------------
__global__ __launch_bounds__(256) void wcvt(const float* __restrict__ s,
                                            unsigned short* __restrict__ d) {
    int i = blockIdx.x * 1024 + threadIdx.x * 4;
    float4 v = *(const float4*)(s + i);
    ushort4 o = make_ushort4(f2bf(v.x), f2bf(v.y), f2bf(v.z), f2bf(v.w));
    *(ushort4*)(d + i) = o;
}

// ------- sum softmax-denominator partials over 16 j-tiles and invert -------
// lpart[jt][zg][i] (16 x 8 x 4096 f32); out l[zg*4096+i] = 1/sum_jt
__global__ __launch_bounds__(256) void recip(const float* __restrict__ lpart,
                                             float* __restrict__ l) {
    int i = blockIdx.x * 256 + threadIdx.x;   // 8192 float4 groups
    float4 s = make_float4(0.f, 0.f, 0.f, 0.f);
#pragma unroll
    for (int jt = 0; jt < 16; ++jt) {
        float4 v = ((const float4*)(lpart + (size_t)jt * 32768))[i];
        s.x += v.x; s.y += v.y; s.z += v.z; s.w += v.w;
    }
    ((float4*)l)[i] = make_float4(1.f/s.x, 1.f/s.y, 1.f/s.z, 1.f/s.w);
}

// ------- GN apply + transpose: x[b][c][hw] fp32 -> h[(b*4096+hw)][c] bf16 -------
__global__ __launch_bounds__(256) void gn_apply(const float* __restrict__ x,
                                                const float* __restrict__ stats,
                                                const float* __restrict__ gamma,
                                                const float* __restrict__ beta,
                                                unsigned short* __restrict__ h) {
    __shared__ unsigned short t[64][72];  // [hw_local][c_local], pad 72
    int b = blockIdx.z, c0 = blockIdx.y * 64, hw0 = blockIdx.x * 64;
    int tid = threadIdx.x;
#pragma unroll
    for (int rep = 0; rep < 4; ++rep) {
        int lin = rep * 256 + tid;         // 1024 = 64 c-rows x 16 float4
        int row = lin >> 4;                // c_local
        int c4  = lin & 15;                // float4 idx along hw
        int c   = c0 + row;
        const float4* src = (const float4*)(x + ((size_t)(b*512 + c) << 12) + hw0);
        float4 v = src[c4];
        int sidx = b*32 + (c >> 4);
        float mu = stats[sidx], rs = stats[256 + sidx];
        float ga = gamma[c] * rs, be = beta[c] - mu * ga;
        t[c4*4+0][row] = f2bf(v.x * ga + be);
        t[c4*4+1][row] = f2bf(v.y * ga + be);
        t[c4*4+2][row] = f2bf(v.z * ga + be);
        t[c4*4+3][row] = f2bf(v.w * ga + be);
    }
    __syncthreads();
#pragma unroll
    for (int rep = 0; rep < 2; ++rep) {
        int lin = rep * 256 + tid;         // 512 = 64 hw-rows x 8 groups
        int row = lin >> 3;                // hw_local
        int u8  = lin & 7;
        unsigned short* dst = h + (((size_t)(b*4096 + hw0 + row)) << 9) + c0 + u8*8;
        *(short8*)dst = *(const short8*)&t[row][u8*8];
    }
}

// ---------------- universal 128x128 bf16 MFMA GEMM, BK=64 (reg-staged, proven) ----
// C[m,n] = sum_k A[m,k] * B[n,k]
// mode 1: out bf16, out[m*ldo+n] = bf16(acc + bias[m])                    (vT proj)
// mode 2: out fp32 d_out[b][m][hw], n = b*4096+hw:
//           (sum over B AND B2 K-passes) * rlvec[n] + bias[m] + resid     (o-proj)
//   B/B2 are the split-K PV partials -> the combine (old addcvt) is folded into
//   the K-loop: two K=512 passes accumulate into the same f32 acc.
__global__ __launch_bounds__(256, 2) void gemm_bt(const unsigned short* __restrict__ A,
                                                  int lda, long aZs,
                                                  const unsigned short* __restrict__ B,
                                                  int ldb, long bZs,
                                                  const unsigned short* __restrict__ B2,
                                                  const float* __restrict__ bias,
                                                  const float* __restrict__ resid,
                                                  const float* __restrict__ lvec,
                                                  void* __restrict__ out,
                                                  long ldo, long oZs,
                                                  int K, int mode, float scale) {
    __shared__ unsigned short As[128][72], Bs[128][72];  // 64-wide K-slab, pad 72
    int z = blockIdx.z;
    A += (size_t)z * aZs;
    B += (size_t)z * bZs;
    unsigned short* outu = (unsigned short*)out + (size_t)z * oZs;
    int m0 = blockIdx.y * 128, n0 = blockIdx.x * 128;
    int tid = threadIdx.x, w = tid >> 6, l = tid & 63;
    int lr = l & 15, lq = l >> 4, lk = lq * 8;
    int rbase = (w >> 1) * 64, cbase = (w & 1) * 64;
    f32x4 acc[4][4] = {};
    int passes = (mode == 2) ? 2 : 1;
    const unsigned short* Bsrc = B;
    for (int ps = 0; ps < passes; ++ps) {
        if (ps) Bsrc = B2;
        for (int k0 = 0; k0 < K; k0 += 64) {
            __syncthreads();
#pragma unroll
            for (int p = 0; p < 4; ++p) {
                int lin = p * 256 + tid;           // 1024 = 128 rows x 8 short8
                int r = lin >> 3, qq = lin & 7;
                *(short8*)&As[r][qq*8] = *(const short8*)(A + (size_t)(m0 + r)*lda + k0 + qq*8);
                *(short8*)&Bs[r][qq*8] = *(const short8*)(Bsrc + (size_t)(n0 + r)*ldb + k0 + qq*8);
            }
            __syncthreads();
            short8 af[4][2], bfv[4][2];
#pragma unroll
            for (int i = 0; i < 4; ++i)
#pragma unroll
                for (int ks = 0; ks < 2; ++ks) {
                    af[i][ks]  = *(const short8*)&As[rbase + i*16 + lr][ks*32 + lk];
                    bfv[i][ks] = *(const short8*)&Bs[cbase + i*16 + lr][ks*32 + lk];
                }
#pragma unroll
            for (int ks = 0; ks < 2; ++ks)
#pragma unroll
                for (int i = 0; i < 4; ++i)
#pragma unroll
                    for (int j = 0; j < 4; ++j)
                        acc[i][j] = __builtin_amdgcn_mfma_f32_16x16x32_bf16(af[i][ks], bfv[j][ks], acc[i][j], 0, 0, 0);
        }
    }
    int lq4 = lq * 4;
    if (mode == 2) {
        // reciprocal denominators: one load per output column group, hoisted
        float rlv[4];
#pragma unroll
        for (int j = 0; j < 4; ++j) rlv[j] = lvec[n0 + cbase + j*16 + lr];
        float* outf = (float*)out;
#pragma unroll
        for (int i = 0; i < 4; ++i) {
            int rowg = m0 + rbase + i*16 + lq4;
            float4 bq4 = *(const float4*)(bias + rowg);   // rowg % 4 == 0
            float bb[4] = {bq4.x, bq4.y, bq4.z, bq4.w};
            size_t ad[16];
            float lres[16];
#pragma unroll
            for (int j = 0; j < 4; ++j) {
                int colg = n0 + cbase + j*16 + lr;
                size_t base = ((size_t)(colg >> 12)) * 2097152 + (size_t)(colg & 4095);
#pragma unroll
                for (int r = 0; r < 4; ++r) {
                    ad[j*4+r] = base + (size_t)(rowg + r) * 4096;
                    lres[j*4+r] = resid[ad[j*4+r]];
                }
            }
#pragma unroll
            for (int j = 0; j < 4; ++j)
#pragma unroll
                for (int r = 0; r < 4; ++r)
                    outf[ad[j*4+r]] = acc[i][j][r] * rlv[j] + bb[r] + lres[j*4+r];
        }
        return;
    }
#pragma unroll
    for (int i = 0; i < 4; ++i) {
        int rowg = m0 + rbase + i*16 + lq4;
#pragma unroll
        for (int j = 0; j < 4; ++j) {
            int colg = n0 + cbase + j*16 + lr;
#pragma unroll
            for (int r = 0; r < 4; ++r)
                outu[(size_t)(rowg + r) * ldo + colg] = f2bf(acc[i][j][r] + bias[rowg + r]);
        }
    }
}

// ---------------- merged q+k projection: stage h-tile ONCE, two weight tiles ----
// q[m,n] = alpha*(h[m,:] wq[n,:] + bq[n]); k[m,n] = h[m,:] wk[n,:] + bk[n]
// 3 LDS tiles (55 KB) -> still 2 blocks/CU. Halves the h re-fetch vs 2 launches.
__global__ __launch_bounds__(256, 2) void qk2(const unsigned short* __restrict__ A,
                                              const unsigned short* __restrict__ Wq,
                                              const unsigned short* __restrict__ Wk,
                                              const float* __restrict__ biasq,
                                              const float* __restrict__ biask,
                                              unsigned short* __restrict__ qo,
                                              unsigned short* __restrict__ ko) {
    __shared__ unsigned short As[128][72], Bq[128][72], Bk[128][72];
    int m0 = blockIdx.y * 128, n0 = blockIdx.x * 128;
    int tid = threadIdx.x, w = tid >> 6, l = tid & 63;
    int lr = l & 15, lq = l >> 4, lk = lq * 8;
    int rbase = (w >> 1) * 64, cbase = (w & 1) * 64;
    f32x4 aq[4][4] = {}, ak[4][4] = {};
    for (int k0 = 0; k0 < 512; k0 += 64) {
        __syncthreads();
#pragma unroll
        for (int p = 0; p < 4; ++p) {
            int lin = p * 256 + tid;           // 1024 = 128 rows x 8 short8
            int r = lin >> 3, qq = lin & 7;
            *(short8*)&As[r][qq*8] = *(const short8*)(A  + (size_t)(m0 + r)*512 + k0 + qq*8);
            *(short8*)&Bq[r][qq*8] = *(const short8*)(Wq + (size_t)(n0 + r)*512 + k0 + qq*8);
            *(short8*)&Bk[r][qq*8] = *(const short8*)(Wk + (size_t)(n0 + r)*512 + k0 + qq*8);
        }
        __syncthreads();
#pragma unroll
        for (int ks = 0; ks < 2; ++ks) {
            short8 af[4], bfq[4], bfk[4];
#pragma unroll
            for (int i = 0; i < 4; ++i) {
                af[i]  = *(const short8*)&As[rbase + i*16 + lr][ks*32 + lk];
                bfq[i] = *(const short8*)&Bq[cbase + i*16 + lr][ks*32 + lk];
                bfk[i] = *(const short8*)&Bk[cbase + i*16 + lr][ks*32 + lk];
            }
#pragma unroll
            for (int i = 0; i < 4; ++i)
#pragma unroll
                for (int j = 0; j < 4; ++j) {
                    aq[i][j] = __builtin_amdgcn_mfma_f32_16x16x32_bf16(af[i], bfq[j], aq[i][j], 0, 0, 0);
                    ak[i][j] = __builtin_amdgcn_mfma_f32_16x16x32_bf16(af[i], bfk[j], ak[i][j], 0, 0, 0);
                }
        }
    }
    int lq4 = lq * 4;
#pragma unroll
    for (int i = 0; i < 4; ++i) {
        int rowg = m0 + rbase + i*16 + lq4;
#pragma unroll
        for (int j = 0; j < 4; ++j) {
            int colg = n0 + cbase + j*16 + lr;
            float bqv = biasq[colg], bkv = biask[colg];
#pragma unroll
            for (int r = 0; r < 4; ++r) {
                qo[(size_t)(rowg + r) * 512 + colg] = f2bf((aq[i][j][r] + bqv) * ALPHA);
                ko[(size_t)(rowg + r) * 512 + colg] = f2bf(ak[i][j][r] + bkv);
            }
        }
    }
}

// =====================================================================
// 8-phase-style 256x256 MFMA core (T1+T2+T3+T4+T5), BK=64, 512 thr, 8 waves (2Mx4N)
// LDS 128 KiB: As/Bs [2][256][64] linear, both-sides XOR swizzle (verified 0-conflict):
// source col pre-permuted ((l&7)^(l>>3))*8; read addr ^ (lr&7)<<4.
// Phase: {reads; stage; BAR; lgkmcnt(0); setprio(1); 16 MFMA; setprio(0); BAR}.
// vmcnt(4) once per K-tile at ph4 (counted, never 0 in steady state — T4).
// Ledger: ph1 +SG_A(t+1); ph2/3 +SG_B(t+2); ph4 vmcnt(4) drains A(t+1)+B(t+1),
// leaves B(t+2) in flight. Buffer WAR audited (see R5 notes).
// Output layout (verified): acc[mi][nj][r] = C[row][col],
//   row (FIRST operand) = wr*128 + mi*16 + lq*4 + r, col (SECOND) = wc*64 + nj*16 + lr.
// =====================================================================
__device__ __forceinline__ void mm8_core(const unsigned short* __restrict__ A, int lda,
                                         const unsigned short* __restrict__ B, int ldb,
                                         int T,
                                         unsigned short (*As)[256][64],
                                         unsigned short (*Bs)[256][64],
                                         f32x4 acc[8][4]) {
    int tid = threadIdx.x, w = tid >> 6, l = tid & 63;
    int wr = w >> 2, wc = w & 3;
    int lr = l & 15, lq = l >> 4;
    int rsub = l >> 3, colp = ((l & 7) ^ rsub) << 3;   // pre-permuted source col
    int sw = (lr & 7) << 4;                             // read-side XOR
    int aw = w * 8;                                     // wave row offset in 64-row span

#define SG_A(buf, t_) { \
    const unsigned short* ap = A + (size_t)(t_) * 64; \
    __builtin_amdgcn_global_load_lds(GLO(ap + (size_t)(aw + rsub) * lda + colp),        LDSP(&As[buf][aw][0]), 16, 0, 0); \
    __builtin_amdgcn_global_load_lds(GLO(ap + (size_t)(64 + aw + rsub) * lda + colp),   LDSP(&As[buf][64 + aw][0]), 16, 0, 0); \
    __builtin_amdgcn_global_load_lds(GLO(ap + (size_t)(128 + aw + rsub) * lda + colp),  LDSP(&As[buf][128 + aw][0]), 16, 0, 0); \
    __builtin_amdgcn_global_load_lds(GLO(ap + (size_t)(192 + aw + rsub) * lda + colp),  LDSP(&As[buf][192 + aw][0]), 16, 0, 0); }
#define SG_B(buf, t_, h_) { \
    const unsigned short* bp = B + (size_t)(t_) * 64; int rb = (h_) * 128 + aw; \
    __builtin_amdgcn_global_load_lds(GLO(bp + (size_t)(rb + rsub) * ldb + colp),       LDSP(&Bs[buf][rb][0]), 16, 0, 0); \
    __builtin_amdgcn_global_load_lds(GLO(bp + (size_t)(rb + 64 + rsub) * ldb + colp),  LDSP(&Bs[buf][rb + 64][0]), 16, 0, 0); }
#define RD_B() { \
    const char* bsb = (const char*)Bs[cur]; \
    _Pragma("unroll") for (int nj = 0; nj < 4; ++nj) \
    _Pragma("unroll") for (int ks = 0; ks < 2; ++ks) { \
        int row = wc * 64 + nj * 16 + lr; \
        bf[nj][ks] = *(const short8*)(bsb + (((row << 7) + (ks << 6) + (lq << 4)) ^ sw)); } }
#define RD_A(p_) { \
    const char* asb = (const char*)As[cur]; \
    _Pragma("unroll") for (int i = 0; i < 2; ++i) \
    _Pragma("unroll") for (int ks = 0; ks < 2; ++ks) { \
        int row = wr * 128 + ((p_) * 2 + i) * 16 + lr; \
        af[i][ks] = *(const short8*)(asb + (((row << 7) + (ks << 6) + (lq << 4)) ^ sw)); } }
#define MM(p_) { \
    _Pragma("unroll") for (int ks = 0; ks < 2; ++ks) \
    _Pragma("unroll") for (int i = 0; i < 2; ++i) \
    _Pragma("unroll") for (int nj = 0; nj < 4; ++nj) \
        acc[(p_) * 2 + i][nj] = __builtin_amdgcn_mfma_f32_16x16x32_bf16(af[i][ks], bf[nj][ks], acc[(p_) * 2 + i][nj], 0, 0, 0); }
#define LGKM0 { asm volatile("s_waitcnt lgkmcnt(0)" ::: "memory"); __builtin_amdgcn_sched_barrier(0); }
#define VMC4 { asm volatile("s_waitcnt vmcnt(4)" ::: "memory"); __builtin_amdgcn_sched_barrier(0); }
#define VMC0 { asm volatile("s_waitcnt vmcnt(0)" ::: "memory"); __builtin_amdgcn_sched_barrier(0); }
#define BAR __builtin_amdgcn_s_barrier()

    // prologue: tile 0 (A+B) -> buf0; B(1) -> buf1; drain tile 0, keep B(1) in flight
    SG_A(0, 0); SG_B(0, 0, 0); SG_B(0, 0, 1);
    if (T > 1) { SG_B(1, 1, 0); SG_B(1, 1, 1); VMC4; } else { VMC0; }
    BAR;
    for (int t = 0; t < T; ++t) {
        int cur = t & 1, nxt = cur ^ 1;
        short8 bf[4][2], af[2][2];
        // phase 1
        RD_B(); RD_A(0);
        if (t + 1 < T) SG_A(nxt, t + 1);
        BAR; LGKM0;
        __builtin_amdgcn_s_setprio(1); MM(0); __builtin_amdgcn_s_setprio(0);
        BAR;
        // phase 2
        RD_A(1);
        if (t + 2 < T) SG_B(cur, t + 2, 0);
        BAR; LGKM0;
        __builtin_amdgcn_s_setprio(1); MM(1); __builtin_amdgcn_s_setprio(0);
        BAR;
        // phase 3
        RD_A(2);
        if (t + 2 < T) SG_B(cur, t + 2, 1);
        BAR; LGKM0;
        __builtin_amdgcn_s_setprio(1); MM(2); __builtin_amdgcn_s_setprio(0);
        BAR;
        // phase 4
        RD_A(3);
        if (t + 2 < T) { VMC4; } else { VMC0; }
        BAR; LGKM0;
        __builtin_amdgcn_s_setprio(1); MM(3); __builtin_amdgcn_s_setprio(0);
        BAR;
    }
#undef SG_A
#undef SG_B
#undef RD_B
#undef RD_A
#undef MM
#undef LGKM0
#undef VMC4
#undef VMC0
#undef BAR
}

// ---------------- S pass (SWAPPED operands): S^[j][i] tiles = k q^T ----------------
// acc[mi][nj][r] = S[i][j], j = m0+wr*128+mi*16+lq*4+r (lane-consecutive over r),
// i = n0+wc*64+nj*16+lr. P = bf16(exp(S)) written as packed ushort4 (8B/lane).
// Row-sums: per-lane 32-j sum -> shfl over lq -> LDS cross-wave (wr) combine
// (reusing As, K-loop done) -> ONE store per (jtile,i) into lpart — NO atomics.
// lpart[jt][zofs+z][i] reduced later by recip.
__global__ __launch_bounds__(512, 2) void s8(const unsigned short* __restrict__ q,
                                             const unsigned short* __restrict__ k,
                                             float* __restrict__ lpart,
                                             unsigned short* __restrict__ P0,
                                             unsigned short* __restrict__ P1,
                                             int zofs, int nwg) {
    __shared__ unsigned short As[2][256][64], Bs[2][256][64];  // 128 KiB
    int wk = (int)(blockIdx.x & 7) * (nwg >> 3) + (int)(blockIdx.x >> 3);
    int z = wk >> 8, rem = wk & 255;
    int m0 = (rem >> 4) << 8, n0 = (rem & 15) << 8;   // m0 = j-tile, n0 = i-tile
    const unsigned short* A = k + (size_t)z * 2097152 + (size_t)m0 * 512;  // K first!
    const unsigned short* B = q + (size_t)z * 2097152 + (size_t)n0 * 512;
    f32x4 acc[8][4] = {};
    mm8_core(A, 512, B, 512, 8, As, Bs, acc);
    unsigned short* Pz = (z < 2) ? P0 + (size_t)z * 16777216
                                 : P1 + (size_t)(z - 2) * 16777216;
    int tid = threadIdx.x, w = tid >> 6, l = tid & 63;
    int wr = w >> 2, wc = w & 3, lr = l & 15, lq = l >> 4, lq4 = lq * 4;
    int jb = m0 + wr * 128;            // wave's j-strip base
    float* lsum = (float*)As;          // K-loop done; mm8_core's final BAR passed
#pragma unroll
    for (int nj = 0; nj < 4; ++nj) {
        int iloc = wc * 64 + nj * 16 + lr;
        unsigned short* prow = Pz + (size_t)(n0 + iloc) * 4096 + jb + lq4;
        float rs = 0.f;
#pragma unroll
        for (int mi = 0; mi < 8; ++mi) {
            float e0 = __expf(acc[mi][nj][0]);
            float e1 = __expf(acc[mi][nj][1]);
            float e2 = __expf(acc[mi][nj][2]);
            float e3 = __expf(acc[mi][nj][3]);
            rs += (e0 + e1) + (e2 + e3);
            ushort4 pk = make_ushort4(f2bf(e0), f2bf(e1), f2bf(e2), f2bf(e3));
            *(ushort4*)(prow + mi * 16) = pk;
        }
        rs += __shfl_xor(rs, 16);
        rs += __shfl_xor(rs, 32);
        if (lq == 0) lsum[wr * 256 + iloc] = rs;
    }
    __syncthreads();
    if (tid < 256) {
        float v = lsum[tid] + lsum[256 + tid];
        lpart[(size_t)(m0 >> 8) * 32768 + (size_t)(zofs + z) * 4096 + n0 + tid] = v;
    }
}

// ---------------- PV pass: split-K=2, 256x256 tiles -> bf16 partials ----------------
// partial[s][z][m][n] = sum_{k in half s} P[z][m][k] * vt[n][(zofs+z)*4096 + k]
// P batches 0,1 at P0 (+z*16M), batches 2,3 at P1. Partials into dead qb/kb regions;
// the combine is folded into the o-proj GEMM (two K-passes).
__global__ __launch_bounds__(512, 2) void pv8(const unsigned short* __restrict__ P0,
                                              const unsigned short* __restrict__ P1,
                                              const unsigned short* __restrict__ vt,
                                              unsigned short* __restrict__ part0,
                                              unsigned short* __restrict__ part1,
                                              int zofs, int nwg) {
    __shared__ unsigned short As[2][256][64], Bs[2][256][64];  // 128 KiB
    int wk = (int)(blockIdx.x & 7) * (nwg >> 3) + (int)(blockIdx.x >> 3);
    int half = nwg >> 1;
    int s = (wk >= half) ? 1 : 0;
    int rem = wk - s * half;
    int z = rem >> 5, t2 = rem & 31;                    // 32 tiles/batch: 16 m x 2 n
    int m0 = (t2 >> 1) << 8, n0 = (t2 & 1) << 8;
    const unsigned short* Pz = (z < 2) ? P0 + (size_t)z * 16777216
                                       : P1 + (size_t)(z - 2) * 16777216;
    const unsigned short* A = Pz + (size_t)m0 * 4096 + (size_t)s * 2048;
    const unsigned short* B = vt + (size_t)n0 * 32768 + (size_t)(zofs + z) * 4096 + (size_t)s * 2048;
    f32x4 acc[8][4] = {};
    mm8_core(A, 4096, B, 32768, 32, As, Bs, acc);
    unsigned short* pp = (s ? part1 : part0) + (size_t)z * 2097152 + (size_t)m0 * 512 + n0;
    int tid = threadIdx.x, w = tid >> 6, l = tid & 63;
    int wr = w >> 2, wc = w & 3, lr = l & 15, lq4 = (l >> 4) * 4;
#pragma unroll
    for (int mi = 0; mi < 8; ++mi)
#pragma unroll
        for (int nj = 0; nj < 4; ++nj)
#pragma unroll
            for (int r = 0; r < 4; ++r)
                pp[(size_t)(wr * 128 + mi * 16 + lq4 + r) * 512 + wc * 64 + nj * 16 + lr] = f2bf(acc[mi][nj][r]);
}

extern "C" void kernel_launch(void* const* d_in, const int* in_sizes, int n_in,
                              void* d_out, int out_size, void* d_ws, size_t ws_size,
                              hipStream_t stream) {
    const float* x     = (const float*)d_in[0];
    const float* gamma = (const float*)d_in[1];
    const float* beta  = (const float*)d_in[2];
    const float* wq = (const float*)d_in[3];  const float* bq = (const float*)d_in[4];
    const float* wk = (const float*)d_in[5];  const float* bk = (const float*)d_in[6];
    const float* wv = (const float*)d_in[7];  const float* bv = (const float*)d_in[8];
    const float* wo = (const float*)d_in[9];  const float* bo = (const float*)d_in[10];

    // ---- base workspace layout (proven, ends at 136,448,000 B) ----
    char* wsp = (char*)d_ws;
    float* stats        = (float*)wsp;                    //   2 KB
    unsigned short* wqb = (unsigned short*)(wsp + 2048);  // 512 KB each
    unsigned short* wkb = wqb + 262144;
    unsigned short* wvb = wkb + 262144;
    unsigned short* wob = wvb + 262144;
    unsigned short* h   = wob + 262144;                   // 32 MB [B*HW, C] bf16
    unsigned short* qb  = h  + 16777216;                  // 32 MB
    unsigned short* kb  = qb + 16777216;                  // 32 MB
    unsigned short* vtb = kb + 16777216;                  // 32 MB [C, B*HW] bf16
    float* lbuf         = (float*)(vtb + 16777216);       // 128 KB softmax denoms
    unsigned short* Pw  = (unsigned short*)(lbuf + 32768);// mid path: +64 MB, ends 203.6 MB
    unsigned short* Pd  = (unsigned short*)d_out;         // 64 MB: 2 batches of P
    float* lpart        = (float*)h;                      // 2 MB, h dead after vT GEMM

    // mid path needs 203,556,864 B total
    const bool mid = ws_size >= 204000000ull;

    gn_stats<<<256, 256, 0, stream>>>(x, stats);
    wcvt<<<256, 256, 0, stream>>>(wq, wqb);
    wcvt<<<256, 256, 0, stream>>>(wk, wkb);
    wcvt<<<256, 256, 0, stream>>>(wv, wvb);
    wcvt<<<256, 256, 0, stream>>>(wo, wob);
    gn_apply<<<dim3(64, 8, 8), 256, 0, stream>>>(x, stats, gamma, beta, h);

    // q = alpha*(h wq^T + bq), k = h wk^T + bk  : [32768 x 512] — ONE launch, h staged once
    qk2<<<dim3(4, 256), 256, 0, stream>>>(h, wqb, wkb, bq, bk, qb, kb);
    // vT[c, pos] = wv h^T + bv : [512 x 32768]
    gemm_bt<<<dim3(256, 4), 256, 0, stream>>>(wvb, 512, 0, h, 512, 0, nullptr, bv, nullptr, nullptr,
                                              vtb, 32768, 0, 512, 1, 1.0f);

    const long QS = (long)4096 * 512;   // per-batch q/k stride (elements)
    if (mid) {
        // ---- 2 chunks x 4 batches: P in d_out (2) + ws tail (2) ----
        // One s8 launch covers 4 batches (z<2 -> Pd, else Pw).
        // After each chunk's S-pass, that chunk's qb/kb regions are dead ->
        // split-K partial buffers land there; chunk c batches occupy
        // qb/kb + b*QS for b in [4c,4c+4) -> final layout is contiguous over all b.
        for (int c = 0; c < 2; ++c) {
            size_t z0 = (size_t)c * 4;
            s8<<<1024, 512, 0, stream>>>(qb + z0 * QS, kb + z0 * QS,
                                         lpart, Pd, Pw, (int)z0, 1024);
            pv8<<<256, 512, 0, stream>>>(Pd, Pw, vtb,
                                         qb + z0 * QS, kb + z0 * QS, (int)z0, 256);
        }
    } else {
        // ---- 4 chunks x 2 batches: P in d_out only ----
        for (int c = 0; c < 4; ++c) {
            size_t z0 = (size_t)c * 2;
            s8<<<512, 512, 0, stream>>>(qb + z0 * QS, kb + z0 * QS,
                                        lpart, Pd, Pd, (int)z0, 512);
            pv8<<<128, 512, 0, stream>>>(Pd, Pd, vtb,
                                         qb + z0 * QS, kb + z0 * QS, (int)z0, 128);
        }
    }
    // reduce l-partials over 16 j-tiles and invert -> lbuf
    recip<<<32, 256, 0, stream>>>(lpart, lbuf);
    // out[b,c,hw] = (wo (p0+p1)^T) * (1/l) + bo + x — split-K combine folded in
    // (two K=512 passes over B=qb partials and B2=kb partials).
    gemm_bt<<<dim3(256, 4), 256, 0, stream>>>(wob, 512, 0, qb, 512, 0, kb, bo, x, lbuf,
                                              d_out, 0, 0, 512, 2, 1.0f);
}